// Round 23
// baseline (349.110 us; speedup 1.0000x reference)
//
#include <hip/hip_runtime.h>
#include <hip/hip_bf16.h>

#define T_TOKENS 16384
#define DMODEL 512
#define FFEAT 64
#define DFEMB 64
#define RIN 576
#define DRH 128
#define NG 8
#define NES 2
#define NE 16
#define DHID 256

typedef float f32x4 __attribute__((ext_vector_type(4)));
typedef _Float16 f16x8 __attribute__((ext_vector_type(8)));
#define MFMA16F(a, b, c) __builtin_amdgcn_mfma_f32_16x16x32_f16((a), (b), (c), 0, 0, 0)
#define WAIT_VM(N) asm volatile("s_waitcnt vmcnt(" #N ")" ::: "memory")

__device__ __forceinline__ float gelu_f(float x) {
    return 0.5f * x * (1.0f + erff(x * 0.7071067811865476f));
}
__device__ __forceinline__ unsigned short f2h(float x) {
    _Float16 h = (_Float16)x;
    union { _Float16 f; unsigned short u; } v; v.f = h;
    return v.u;
}
__device__ __forceinline__ float h2f(unsigned short u) {
    union { unsigned short u; _Float16 f; } v; v.u = u;
    return (float)v.f;
}
__device__ __forceinline__ void gl_lds16(const unsigned short* g, unsigned short* l) {
    __builtin_amdgcn_global_load_lds(
        (const __attribute__((address_space(1))) unsigned int*)g,
        (__attribute__((address_space(3))) unsigned int*)l, 16, 0, 0);
}

// ---------- Mega kernel 1: all independent front-end jobs in one launch ----------
// job ranges (block id): [0,4096) prep (also seeds out=hidden) | [.., +264) fold_ps
//   | [.., +40) fold_ir | [.., +1024) bsplitT2 (psW1/irW1) | [.., +4096) bsplitTE (eW1/eW2)
#define MG_PREP 4096
#define MG_FPS  264
#define MG_FIR  40
#define MG_T2   1024
#define MG_TE   4096
#define MG_TOTAL (MG_PREP + MG_FPS + MG_FIR + MG_T2 + MG_TE)

__global__ __launch_bounds__(256) void k_mega1(
    const float* __restrict__ hidden, const float* __restrict__ feat,
    const float* __restrict__ lng, const float* __restrict__ lnb,
    unsigned short* __restrict__ Ahi, int* __restrict__ cz,
    const float* __restrict__ stageW, const float* __restrict__ stageb,
    const float* __restrict__ psW1, const float* __restrict__ psb1,
    float* __restrict__ Dps, float* __restrict__ fbps,
    const float* __restrict__ gfW, const float* __restrict__ gfb,
    const float* __restrict__ irW1, const float* __restrict__ irb1,
    float* __restrict__ Cir, float* __restrict__ fbir,
    unsigned short* __restrict__ Bhi,
    const float* __restrict__ eW1, const float* __restrict__ eW2,
    unsigned short* __restrict__ eW1T, unsigned short* __restrict__ eW2T,
    float* __restrict__ out)
{
    __shared__ float s_t[32][33];
    int bid = blockIdx.x;
    const int tid = threadIdx.x;

    if (bid < MG_PREP) {
        // ---- prep: LN + fp16 swizzled A (+ zero routing counters, + out=hidden seed) ----
        if (bid == 0 && tid < 32) cz[tid] = 0;
        const int t = bid * 4 + (tid >> 6);
        const int lane = tid & 63;
        const float* row = hidden + (size_t)t * DMODEL;
        float4 v0 = ((const float4*)row)[lane * 2 + 0];
        float4 v1 = ((const float4*)row)[lane * 2 + 1];
        // seed residual: out = hidden (k_e2 atomically accumulates expert contributions)
        float* orow = out + (size_t)t * DMODEL;
        ((float4*)orow)[lane * 2 + 0] = v0;
        ((float4*)orow)[lane * 2 + 1] = v1;
        float s = v0.x + v0.y + v0.z + v0.w + v1.x + v1.y + v1.z + v1.w;
        #pragma unroll
        for (int m = 1; m < 64; m <<= 1) s += __shfl_xor(s, m);
        const float mu = s * (1.0f / DMODEL);
        float sq = 0.f;
        { float d;
          d = v0.x - mu; sq += d * d; d = v0.y - mu; sq += d * d;
          d = v0.z - mu; sq += d * d; d = v0.w - mu; sq += d * d;
          d = v1.x - mu; sq += d * d; d = v1.y - mu; sq += d * d;
          d = v1.z - mu; sq += d * d; d = v1.w - mu; sq += d * d; }
        #pragma unroll
        for (int m = 1; m < 64; m <<= 1) sq += __shfl_xor(sq, m);
        const float rstd = rsqrtf(sq * (1.0f / DMODEL) + 1e-5f);
        float4 g0 = ((const float4*)lng)[lane * 2 + 0];
        float4 g1 = ((const float4*)lng)[lane * 2 + 1];
        float4 b0 = ((const float4*)lnb)[lane * 2 + 0];
        float4 b1 = ((const float4*)lnb)[lane * 2 + 1];
        float h[8];
        h[0] = (v0.x - mu) * rstd * g0.x + b0.x;
        h[1] = (v0.y - mu) * rstd * g0.y + b0.y;
        h[2] = (v0.z - mu) * rstd * g0.z + b0.z;
        h[3] = (v0.w - mu) * rstd * g0.w + b0.w;
        h[4] = (v1.x - mu) * rstd * g1.x + b1.x;
        h[5] = (v1.y - mu) * rstd * g1.y + b1.y;
        h[6] = (v1.z - mu) * rstd * g1.z + b1.z;
        h[7] = (v1.w - mu) * rstd * g1.w + b1.w;
        const int q8 = ((t >> 1) & 3) * 8;
        ushort4 H0, H1;
        H0.x = f2h(h[0]); H0.y = f2h(h[1]); H0.z = f2h(h[2]); H0.w = f2h(h[3]);
        H1.x = f2h(h[4]); H1.y = f2h(h[5]); H1.z = f2h(h[6]); H1.w = f2h(h[7]);
        unsigned short* pa = Ahi + (size_t)t * RIN;
        const int dst = (lane >> 2) * 32 + (((lane & 3) * 8) ^ q8);
        *(ushort4*)&pa[dst] = H0;  *(ushort4*)&pa[dst + 4] = H1;
        const float fv = feat[(size_t)t * FFEAT + lane];
        const int fd = DMODEL + (lane & 32) + ((lane & 31) ^ q8);
        pa[fd] = f2h(fv);
        return;
    }
    bid -= MG_PREP;

    if (bid < MG_FPS) {
        // ---- fold_ps: 2 f-slots per 256-thread block ----
        const int g = bid / 33;
        const int f = (bid % 33) * 2 + (tid >> 7);
        const int c = tid & 127;
        const float* Wt = psW1 + (size_t)g * RIN * DRH + (size_t)DMODEL * DRH;
        float acc = 0.f;
        if (f < 64) {
            for (int j = 0; j < DFEMB; ++j) acc = fmaf(stageW[f * DFEMB + j], Wt[(size_t)j * DRH + c], acc);
            Dps[((size_t)g * 64 + f) * DRH + c] = acc;
        } else if (f == 64) {
            for (int j = 0; j < DFEMB; ++j) acc = fmaf(stageb[j], Wt[(size_t)j * DRH + c], acc);
            fbps[g * DRH + c] = acc + psb1[g * DRH + c];
        }
        return;
    }
    bid -= MG_FPS;

    if (bid < MG_FIR) {
        // ---- fold_ir: 2 f-slots per 256-thread block ----
        const int g = bid / 5;
        const int f = (bid % 5) * 2 + (tid >> 7);
        const int c = tid & 127;
        const float* Wt = irW1 + (size_t)g * RIN * DRH + (size_t)DMODEL * DRH;
        float acc = 0.f;
        if (f < 8) {
            for (int j = 0; j < DFEMB; ++j) acc = fmaf(gfW[(size_t)(g * 8 + f) * DFEMB + j], Wt[(size_t)j * DRH + c], acc);
            Cir[((size_t)g * 8 + f) * DRH + c] = acc;
        } else if (f == 8) {
            for (int j = 0; j < DFEMB; ++j) acc = fmaf(gfb[g * DFEMB + j], Wt[(size_t)j * DRH + c], acc);
            fbir[g * DRH + c] = acc + irb1[g * DRH + c];
        }
        return;
    }
    bid -= MG_FIR;

    if (bid < MG_T2) {
        // ---- router main-weight transpose: z=0 psW1, z=1 irW1 ----
        const int x = bid % 64, y = (bid / 64) % 8, z = bid / 512;
        const float* in = z ? irW1 : psW1;
        unsigned short* outHi = Bhi + (z ? (size_t)1024 * RIN : 0);
        const int tilesN = DRH >> 5;
        const int ko = (x / tilesN) << 5;
        const int no = (x % tilesN) << 5;
        const int r = tid >> 3, c0 = (tid & 7) * 4;
        {
            float4 v = *(const float4*)(in + (size_t)y * RIN * DRH + (size_t)(ko + r) * DRH + no + c0);
            s_t[r][c0] = v.x; s_t[r][c0 + 1] = v.y; s_t[r][c0 + 2] = v.z; s_t[r][c0 + 3] = v.w;
        }
        __syncthreads();
        float vv[4];
        #pragma unroll
        for (int j = 0; j < 4; ++j) vv[j] = s_t[c0 + j][r];
        const int col = no + r;
        const int q8 = ((col >> 1) & 3) * 8;
        ushort4 hi;
        hi.x = f2h(vv[0]); hi.y = f2h(vv[1]); hi.z = f2h(vv[2]); hi.w = f2h(vv[3]);
        *(ushort4*)(outHi + (size_t)y * DRH * RIN + (size_t)col * RIN + ko + (c0 ^ q8)) = hi;
        return;
    }
    bid -= MG_T2;

    {
        // ---- expert weight transpose: z=0 eW1 (512x256), z=1 eW2 (256x512) ----
        const int x = bid % 128, y = (bid / 128) % 16, z = bid / 2048;
        const int K = z ? DHID : DMODEL;
        const int N = z ? DMODEL : DHID;
        const float* in = z ? eW2 : eW1;
        unsigned short* outHi = z ? eW2T : eW1T;
        const long BS = (long)DMODEL * DHID;
        const int tilesN = N >> 5;
        const int ko = (x / tilesN) << 5;
        const int no = (x % tilesN) << 5;
        const int r = tid >> 3, c0 = (tid & 7) * 4;
        {
            float4 v = *(const float4*)(in + (size_t)y * BS + (size_t)(ko + r) * N + no + c0);
            s_t[r][c0] = v.x; s_t[r][c0 + 1] = v.y; s_t[r][c0 + 2] = v.z; s_t[r][c0 + 3] = v.w;
        }
        __syncthreads();
        float vv[4];
        #pragma unroll
        for (int j = 0; j < 4; ++j) vv[j] = s_t[c0 + j][r];
        const int col = no + r;
        const int q8 = ((col >> 1) & 3) * 8;
        ushort4 hi;
        hi.x = f2h(vv[0]); hi.y = f2h(vv[1]); hi.z = f2h(vv[2]); hi.w = f2h(vv[3]);
        *(ushort4*)(outHi + (size_t)y * BS + (size_t)col * K + ko + (c0 ^ q8)) = hi;
    }
}

// ---------- Mega kernel 2: fold-dependent jobs (Dps transpose + ir tail) ----------
// [0,64) bsplitT(Dps -> Bhi rows 512.., kOff=512) | [64,72) irtail
__global__ __launch_bounds__(256) void k_mega2(
    const float* __restrict__ Dps, const float* __restrict__ Cir,
    unsigned short* __restrict__ Bhi)
{
    __shared__ float s_t[32][33];
    int bid = blockIdx.x;
    const int tid = threadIdx.x;

    if (bid < 64) {
        // ---- transpose Dps[64][128] (per group) into Bhi cols, kOff=512 ----
        const int x = bid % 8, b = bid / 8;
        const int tilesN = DRH >> 5;                 // 4
        const int ko = (x / tilesN) << 5;            // 0 or 32
        const int no = (x % tilesN) << 5;
        const int r = tid >> 3, c0 = (tid & 7) * 4;
        {
            float4 v = *(const float4*)(Dps + (size_t)b * 64 * DRH + (size_t)(ko + r) * DRH + no + c0);
            s_t[r][c0] = v.x; s_t[r][c0 + 1] = v.y; s_t[r][c0 + 2] = v.z; s_t[r][c0 + 3] = v.w;
        }
        __syncthreads();
        float vv[4];
        #pragma unroll
        for (int j = 0; j < 4; ++j) vv[j] = s_t[c0 + j][r];
        const int col = no + r;
        const int q8 = ((col >> 1) & 3) * 8;
        ushort4 hi;
        hi.x = f2h(vv[0]); hi.y = f2h(vv[1]); hi.z = f2h(vv[2]); hi.w = f2h(vv[3]);
        *(ushort4*)(Bhi + (size_t)b * DRH * RIN + (size_t)col * RIN + 512 + ko + (c0 ^ q8)) = hi;
        return;
    }
    bid -= 64;

    {
        // ---- ir tail rows of B: f-range split across half-blocks ----
        const int g = bid;
        const int c = tid & 127;
        const int h = tid >> 7;
        const int col = 1024 + g * DRH + c;
        const int q8 = ((col >> 1) & 3) * 8;
        unsigned short* ph = Bhi + (size_t)col * RIN + DMODEL;
        for (int f = h * 32; f < h * 32 + 32; ++f) {
            float v = ((f >> 3) == g) ? Cir[((size_t)g * 8 + (f & 7)) * DRH + c] : 0.f;
            const int d = (f & 32) + ((f & 31) ^ q8);
            ph[d] = f2h(v);
        }
    }
}

// ---------- Kernel 2: router GEMM, 8-wave 128x128, depth-3 counted-vmcnt (R13 verified) ----------
__global__ __launch_bounds__(512) void k_rgemm(
    const unsigned short* __restrict__ Ahi, const unsigned short* __restrict__ Bhi,
    const float* __restrict__ fbps, const float* __restrict__ psW2, const float* __restrict__ psb2,
    const float* __restrict__ fbir, const float* __restrict__ irW2, const float* __restrict__ irb2,
    float* __restrict__ glog, float* __restrict__ ilog)
{
    __shared__ unsigned short sAh[3][128 * 32];
    __shared__ unsigned short sBh[3][128 * 32];
    __shared__ float s_red[2][4][64][2];

    const int tid = threadIdx.x, lane = tid & 63, w = tid >> 6;
    const int t0 = blockIdx.x * 128, bn = blockIdx.y;
    const int wm = w >> 2, wn = w & 3;
    const int arow = lane & 15, koff = (lane >> 4) * 8;
    const int q8r = ((arow >> 1) & 3) * 8;

    int aoff[4], boff[2];
    #pragma unroll
    for (int m = 0; m < 4; ++m) aoff[m] = (wm * 64 + m * 16 + arow) * 32 + (koff ^ q8r);
    #pragma unroll
    for (int n = 0; n < 2; ++n) boff[n] = (wn * 32 + n * 16 + arow) * 32 + (koff ^ q8r);

    const int srow = w * 16 + (lane >> 2);
    const int sgr = (lane & 3) * 8;
    const unsigned short* gAh = Ahi + (size_t)(t0 + srow) * RIN + sgr;
    const unsigned short* gBh = Bhi + (size_t)(bn * 128 + srow) * RIN + sgr;

    f32x4 acc[4][2];
    #pragma unroll
    for (int m = 0; m < 4; ++m)
        #pragma unroll
        for (int n = 0; n < 2; ++n) { acc[m][n].x = 0.f; acc[m][n].y = 0.f; acc[m][n].z = 0.f; acc[m][n].w = 0.f; }

    auto STAGE = [&](int b, int kt) {
        const int kk = kt * 32;
        gl_lds16(gAh + kk, &sAh[b][w * 512]);
        gl_lds16(gBh + kk, &sBh[b][w * 512]);
    };

    STAGE(0, 0);
    STAGE(1, 1);
    for (int kt = 0; kt < 18; ++kt) {
        const int slot = kt % 3;
        if (kt + 2 < 18) { STAGE((kt + 2) % 3, kt + 2); WAIT_VM(4); }
        else if (kt + 1 < 18) { WAIT_VM(2); }
        else { WAIT_VM(0); }
        __builtin_amdgcn_s_barrier();
        __builtin_amdgcn_sched_barrier(0);
        f16x8 ah[4];
        #pragma unroll
        for (int m = 0; m < 4; ++m) ah[m] = *(const f16x8*)&sAh[slot][aoff[m]];
        #pragma unroll
        for (int n = 0; n < 2; ++n) {
            f16x8 b = *(const f16x8*)&sBh[slot][boff[n]];
            #pragma unroll
            for (int m = 0; m < 4; ++m) acc[m][n] = MFMA16F(ah[m], b, acc[m][n]);
        }
        __builtin_amdgcn_s_barrier();
    }

    // fused second layer (one group per block)
    const bool isPS = (bn < 8);
    const int g = bn & 7;
    const int q = lane >> 4;
    if (isPS) {
        float r0[4][4] = {};
        #pragma unroll
        for (int n = 0; n < 2; ++n) {
            const int cg = wn * 32 + n * 16 + arow;
            const float b1 = fbps[g * DRH + cg];
            const float w2 = psW2[g * DRH + cg];
            #pragma unroll
            for (int m = 0; m < 4; ++m)
                #pragma unroll
                for (int j = 0; j < 4; ++j)
                    r0[m][j] += gelu_f(acc[m][n][j] + b1) * w2;
        }
        #pragma unroll
        for (int mk = 1; mk < 16; mk <<= 1)
            #pragma unroll
            for (int m = 0; m < 4; ++m)
                #pragma unroll
                for (int j = 0; j < 4; ++j) r0[m][j] += __shfl_xor(r0[m][j], mk);
        if (arow == 0) {
            #pragma unroll
            for (int m = 0; m < 4; ++m)
                #pragma unroll
                for (int j = 0; j < 4; ++j) {
                    s_red[wm][wn][m * 16 + q * 4 + j][0] = r0[m][j];
                }
        }
    } else {
        float r0[4][4] = {}, r1[4][4] = {};
        #pragma unroll
        for (int n = 0; n < 2; ++n) {
            const int cg = wn * 32 + n * 16 + arow;
            const float b1 = fbir[g * DRH + cg];
            const float w20 = irW2[(size_t)(g * DRH + cg) * NES + 0];
            const float w21 = irW2[(size_t)(g * DRH + cg) * NES + 1];
            #pragma unroll
            for (int m = 0; m < 4; ++m)
                #pragma unroll
                for (int j = 0; j < 4; ++j) {
                    const float v = gelu_f(acc[m][n][j] + b1);
                    r0[m][j] = fmaf(v, w20, r0[m][j]);
                    r1[m][j] = fmaf(v, w21, r1[m][j]);
                }
        }
        #pragma unroll
        for (int mk = 1; mk < 16; mk <<= 1)
            #pragma unroll
            for (int m = 0; m < 4; ++m)
                #pragma unroll
                for (int j = 0; j < 4; ++j) {
                    r0[m][j] += __shfl_xor(r0[m][j], mk);
                    r1[m][j] += __shfl_xor(r1[m][j], mk);
                }
        if (arow == 0) {
            #pragma unroll
            for (int m = 0; m < 4; ++m)
                #pragma unroll
                for (int j = 0; j < 4; ++j) {
                    s_red[wm][wn][m * 16 + q * 4 + j][0] = r0[m][j];
                    s_red[wm][wn][m * 16 + q * 4 + j][1] = r1[m][j];
                }
        }
    }
    __syncthreads();
    if (tid < 128) {
        const int row = tid;
        const int wmm = row >> 6, rl = row & 63;
        if (isPS) {
            float v0 = s_red[wmm][0][rl][0] + s_red[wmm][1][rl][0]
                     + s_red[wmm][2][rl][0] + s_red[wmm][3][rl][0];
            glog[(size_t)(t0 + row) * NG + g] = v0 + psb2[g];
        } else {
            float v0 = s_red[wmm][0][rl][0] + s_red[wmm][1][rl][0]
                     + s_red[wmm][2][rl][0] + s_red[wmm][3][rl][0];
            float v1 = s_red[wmm][0][rl][1] + s_red[wmm][1][rl][1]
                     + s_red[wmm][2][rl][1] + s_red[wmm][3][rl][1];
            const size_t bidx = ((size_t)(t0 + row) * NG + g) * NES;
            ilog[bidx + 0] = v0 + irb2[g * NES + 0];
            ilog[bidx + 1] = v1 + irb2[g * NES + 1];
        }
    }
}

// ---------- Kernel 2b: finalize, block-aggregated atomics ----------
#define MARGIN 4e-3f
__global__ __launch_bounds__(256) void hg_finalize2(
    const float* __restrict__ glog_buf, const float* __restrict__ ilog_buf,
    int* __restrict__ counts, int* __restrict__ nfix, int* __restrict__ fix_list,
    int* __restrict__ list_tok, float* __restrict__ list_w, int* __restrict__ list_slot)
{
    __shared__ int s_cnt[NE];
    __shared__ int s_base[NE];
    __shared__ int s_fcnt, s_fbase;

    const int tid = threadIdx.x;
    const int t = blockIdx.x * 256 + tid;
    if (tid < NE) s_cnt[tid] = 0;
    if (tid == 0) s_fcnt = 0;
    __syncthreads();

    float gl[NG];
    *(float4*)&gl[0] = ((const float4*)(glog_buf + (size_t)t * NG))[0];
    *(float4*)&gl[4] = ((const float4*)(glog_buf + (size_t)t * NG))[1];
    int i1 = 0; float m1 = gl[0];
    #pragma unroll
    for (int g = 1; g < NG; ++g) if (gl[g] > m1) { m1 = gl[g]; i1 = g; }
    int i2 = -1; float m2 = -3.4e38f;
    #pragma unroll
    for (int g = 0; g < NG; ++g) if (g != i1 && gl[g] > m2) { m2 = gl[g]; i2 = g; }
    float m3 = -3.4e38f;
    #pragma unroll
    for (int g = 0; g < NG; ++g) if (g != i1 && g != i2 && gl[g] > m3) m3 = gl[g];

    const float ila0 = ilog_buf[((size_t)t * NG + i1) * NES + 0];
    const float ila1 = ilog_buf[((size_t)t * NG + i1) * NES + 1];
    const float ilb0 = ilog_buf[((size_t)t * NG + i2) * NES + 0];
    const float ilb1 = ilog_buf[((size_t)t * NG + i2) * NES + 1];

    const bool flag = ((m2 - m3) < MARGIN) || (fabsf(ila1 - ila0) < MARGIN)
                   || (fabsf(ilb1 - ilb0) < MARGIN);

    const float ex = expf(m2 - m1);
    const float inv = 1.0f / (1.0f + ex);
    const int   gsel[2] = {i1, i2};
    const float wsel[2] = {inv, ex * inv};
    const int   ksel[2] = {(ila1 > ila0) ? 1 : 0, (ilb1 > ilb0) ? 1 : 0};

    int eid[2] = {0, 0}, lo[2] = {0, 0}, fo = 0;
    if (!flag) {
        #pragma unroll
        for (int s = 0; s < 2; ++s) {
            eid[s] = gsel[s] * NES + ksel[s];
            lo[s] = atomicAdd(&s_cnt[eid[s]], 1);
        }
    } else {
        fo = atomicAdd(&s_fcnt, 1);
    }
    __syncthreads();
    if (tid < NE) s_base[tid] = atomicAdd(&counts[tid], s_cnt[tid]);
    if (tid == 16) s_fbase = atomicAdd(nfix, s_fcnt);
    __syncthreads();

    if (!flag) {
        #pragma unroll
        for (int s = 0; s < 2; ++s) {
            const int pos = s_base[eid[s]] + lo[s];
            list_tok[(size_t)eid[s] * T_TOKENS + pos] = t;
            list_w[(size_t)eid[s] * T_TOKENS + pos] = wsel[s];
            list_slot[(size_t)eid[s] * T_TOKENS + pos] = s;
        }
    } else {
        fix_list[s_fbase + fo] = t;
    }
}

// ---------- Kernel 2c: exact fp32 fixup, 4-wave parallel, unrolled ----------
__global__ __launch_bounds__(256) void hg_fixup(
    const float* __restrict__ hidden, const float* __restrict__ feat,
    const float* __restrict__ lng, const float* __restrict__ lnb,
    const float* __restrict__ stageW, const float* __restrict__ stageb,
    const float* __restrict__ gfW, const float* __restrict__ gfb,
    const float* __restrict__ psW1, const float* __restrict__ psb1,
    const float* __restrict__ psW2, const float* __restrict__ psb2,
    const float* __restrict__ irW1, const float* __restrict__ irb1,
    const float* __restrict__ irW2, const float* __restrict__ irb2,
    const int* __restrict__ nfix, const int* __restrict__ fix_list,
    int* __restrict__ counts, int* __restrict__ list_tok, float* __restrict__ list_w,
    int* __restrict__ list_slot)
{
    __shared__ float s_rin[RIN];
    __shared__ float s_tail[2][DFEMB];
    __shared__ float s_gl[NG];
    __shared__ float s_part[4][2];
    __shared__ int s_sel[2];
    __shared__ float s_wsel[2];

    const int tid = threadIdx.x, lane = tid & 63, w = tid >> 6;
    const int nf = nfix[0];
    for (int idx = blockIdx.x; idx < nf; idx += gridDim.x) {
        const int t = fix_list[idx];
        if (w == 0) {
            const float* row = hidden + (size_t)t * DMODEL;
            float4 v0 = ((const float4*)row)[lane * 2 + 0];
            float4 v1 = ((const float4*)row)[lane * 2 + 1];
            float s = v0.x + v0.y + v0.z + v0.w + v1.x + v1.y + v1.z + v1.w;
            #pragma unroll
            for (int m = 1; m < 64; m <<= 1) s += __shfl_xor(s, m);
            const float mu = s * (1.0f / DMODEL);
            float sq = 0.f;
            { float d;
              d = v0.x - mu; sq += d * d; d = v0.y - mu; sq += d * d;
              d = v0.z - mu; sq += d * d; d = v0.w - mu; sq += d * d;
              d = v1.x - mu; sq += d * d; d = v1.y - mu; sq += d * d;
              d = v1.z - mu; sq += d * d; d = v1.w - mu; sq += d * d; }
            #pragma unroll
            for (int m = 1; m < 64; m <<= 1) sq += __shfl_xor(sq, m);
            const float rstd = rsqrtf(sq * (1.0f / DMODEL) + 1e-5f);
            float4 g0 = ((const float4*)lng)[lane * 2 + 0];
            float4 g1 = ((const float4*)lng)[lane * 2 + 1];
            float4 b0 = ((const float4*)lnb)[lane * 2 + 0];
            float4 b1 = ((const float4*)lnb)[lane * 2 + 1];
            s_rin[lane * 8 + 0] = (v0.x - mu) * rstd * g0.x + b0.x;
            s_rin[lane * 8 + 1] = (v0.y - mu) * rstd * g0.y + b0.y;
            s_rin[lane * 8 + 2] = (v0.z - mu) * rstd * g0.z + b0.z;
            s_rin[lane * 8 + 3] = (v0.w - mu) * rstd * g0.w + b0.w;
            s_rin[lane * 8 + 4] = (v1.x - mu) * rstd * g1.x + b1.x;
            s_rin[lane * 8 + 5] = (v1.y - mu) * rstd * g1.y + b1.y;
            s_rin[lane * 8 + 6] = (v1.z - mu) * rstd * g1.z + b1.z;
            s_rin[lane * 8 + 7] = (v1.w - mu) * rstd * g1.w + b1.w;
        } else if (w == 1) {
            float se = stageb[lane];
            #pragma unroll 8
            for (int f = 0; f < FFEAT; ++f)
                se = fmaf(feat[(size_t)t * FFEAT + f], stageW[f * DFEMB + lane], se);
            s_rin[DMODEL + lane] = se;
        }
        __syncthreads();

        #pragma unroll
        for (int gi = 0; gi < 2; ++gi) {
            const int g = w * 2 + gi;
            float a0 = psb1[g * DRH + lane];
            float a1 = psb1[g * DRH + 64 + lane];
            const float* W = psW1 + (size_t)g * RIN * DRH;
            #pragma unroll 8
            for (int k = 0; k < RIN; ++k) {
                const float r = s_rin[k];
                a0 = fmaf(r, W[(size_t)k * DRH + lane], a0);
                a1 = fmaf(r, W[(size_t)k * DRH + 64 + lane], a1);
            }
            float p = gelu_f(a0) * psW2[g * DRH + lane] + gelu_f(a1) * psW2[g * DRH + 64 + lane];
            #pragma unroll
            for (int m = 1; m < 64; m <<= 1) p += __shfl_xor(p, m);
            if (lane == 0) s_gl[g] = p + psb2[g];
        }
        __syncthreads();

        if (tid == 0) {
            int i1 = 0; float m1 = s_gl[0];
            #pragma unroll
            for (int g = 1; g < NG; ++g) if (s_gl[g] > m1) { m1 = s_gl[g]; i1 = g; }
            int i2 = -1; float m2 = -3.4e38f;
            #pragma unroll
            for (int g = 0; g < NG; ++g) if (g != i1 && s_gl[g] > m2) { m2 = s_gl[g]; i2 = g; }
            const float ex = expf(m2 - m1);
            const float inv = 1.0f / (1.0f + ex);
            s_sel[0] = i1; s_sel[1] = i2;
            s_wsel[0] = inv; s_wsel[1] = ex * inv;
        }
        __syncthreads();

        const int pr = w >> 1;
        const int gsel = s_sel[pr];
        if ((w & 1) == 0) {
            float ge = gfb[gsel * DFEMB + lane];
            #pragma unroll
            for (int f = 0; f < 8; ++f)
                ge = fmaf(feat[(size_t)t * FFEAT + gsel * 8 + f],
                          gfW[(size_t)(gsel * 8 + f) * DFEMB + lane], ge);
            s_tail[pr][lane] = ge;
        }
        __syncthreads();

        {
            const int col = (w & 1) * 64 + lane;
            float a = irb1[gsel * DRH + col];
            const float* W = irW1 + (size_t)gsel * RIN * DRH + col;
            #pragma unroll 8
            for (int k = 0; k < DMODEL; ++k)
                a = fmaf(s_rin[k], W[(size_t)k * DRH], a);
            #pragma unroll 8
            for (int k = 0; k < DFEMB; ++k)
                a = fmaf(s_tail[pr][k], W[(size_t)(DMODEL + k) * DRH], a);
            const float v = gelu_f(a);
            float e0 = v * irW2[(size_t)(gsel * DRH + col) * NES + 0];
            float e1 = v * irW2[(size_t)(gsel * DRH + col) * NES + 1];
            #pragma unroll
            for (int m = 1; m < 64; m <<= 1) {
                e0 += __shfl_xor(e0, m);
                e1 += __shfl_xor(e1, m);
            }
            if (lane == 0) { s_part[w][0] = e0; s_part[w][1] = e1; }
        }
        __syncthreads();

        if (tid == 0) {
            #pragma unroll
            for (int p2 = 0; p2 < 2; ++p2) {
                const float e0 = s_part[p2 * 2][0] + s_part[p2 * 2 + 1][0];
                const float e1 = s_part[p2 * 2][1] + s_part[p2 * 2 + 1][1];
                const int eid = s_sel[p2] * NES + ((e1 > e0) ? 1 : 0);
                const int pos = atomicAdd(&counts[eid], 1);
                list_tok[(size_t)eid * T_TOKENS + pos] = t;
                list_w[(size_t)eid * T_TOKENS + pos] = s_wsel[p2];
                list_slot[(size_t)eid * T_TOKENS + pos] = p2;
            }
        }
        __syncthreads();
    }
}

// ---------- Kernel 3a: expert GEMM1 -> ehbuf (depth-3 pipeline) ----------
__global__ __launch_bounds__(256) void k_e1(
    const unsigned short* __restrict__ Ahi,
    const unsigned short* __restrict__ eW1T, const float* __restrict__ eb1,
    const int* __restrict__ counts, const int* __restrict__ list_tok,
    const int* __restrict__ list_slot, unsigned short* __restrict__ ehbuf)
{
    __shared__ unsigned short sA[3][64 * 32];
    __shared__ unsigned short sB[3][256 * 32];
    __shared__ int s_tok[64];
    __shared__ int s_pair[64];

    const int e = blockIdx.y;
    const int cnt = counts[e];
    const int base = blockIdx.x * 64;
    if (base >= cnt) return;
    const int nrow = min(64, cnt - base);
    const int tid = threadIdx.x, lane = tid & 63, w = tid >> 6;

    if (tid < 64) {
        const int src = base + ((tid < nrow) ? tid : (nrow - 1));
        s_tok[tid] = list_tok[(size_t)e * T_TOKENS + src];
        s_pair[tid] = s_tok[tid] * 2 + list_slot[(size_t)e * T_TOKENS + src];
    }
    __syncthreads();

    const int srow = w * 16 + (lane >> 2);
    const int stok = s_tok[srow];
    const int qcor = ((srow >> 1) & 3) ^ ((stok >> 1) & 3);
    const unsigned short* gA = Ahi + (size_t)stok * RIN + 8 * ((lane & 3) ^ qcor);
    const int sgr = (lane & 3) * 8;
    const unsigned short* gB[4];
    #pragma unroll
    for (int i = 0; i < 4; ++i)
        gB[i] = eW1T + (size_t)e * DHID * DMODEL + (size_t)(w * 64 + i * 16 + (lane >> 2)) * DMODEL + sgr;

    const int arow = lane & 15, koff = (lane >> 4) * 8;
    const int q8r = ((arow >> 1) & 3) * 8;
    int aoff[4], boff[4];
    #pragma unroll
    for (int m = 0; m < 4; ++m) aoff[m] = (m * 16 + arow) * 32 + (koff ^ q8r);
    #pragma unroll
    for (int n = 0; n < 4; ++n) boff[n] = (w * 64 + n * 16 + arow) * 32 + (koff ^ q8r);

    f32x4 acc[4][4];
    #pragma unroll
    for (int m = 0; m < 4; ++m)
        #pragma unroll
        for (int n = 0; n < 4; ++n) { acc[m][n].x = 0.f; acc[m][n].y = 0.f; acc[m][n].z = 0.f; acc[m][n].w = 0.f; }

    auto STAGE = [&](int b, int kt) {
        const int kk = kt * 32;
        gl_lds16(gA + kk, &sA[b][w * 512]);
        #pragma unroll
        for (int i = 0; i < 4; ++i) gl_lds16(gB[i] + kk, &sB[b][w * 2048 + i * 512]);
    };

    STAGE(0, 0);
    STAGE(1, 1);
    for (int kt = 0; kt < 16; ++kt) {
        const int slot = kt % 3;
        if (kt + 2 < 16) { STAGE((kt + 2) % 3, kt + 2); WAIT_VM(10); }
        else if (kt + 1 < 16) { WAIT_VM(5); }
        else { WAIT_VM(0); }
        __builtin_amdgcn_s_barrier();
        __builtin_amdgcn_sched_barrier(0);
        f16x8 a[4];
        #pragma unroll
        for (int m = 0; m < 4; ++m) a[m] = *(const f16x8*)&sA[slot][aoff[m]];
        #pragma unroll
        for (int n = 0; n < 4; ++n) {
            f16x8 b = *(const f16x8*)&sB[slot][boff[n]];
            #pragma unroll
            for (int m = 0; m < 4; ++m) acc[m][n] = MFMA16F(a[m], b, acc[m][n]);
        }
        __builtin_amdgcn_s_barrier();
    }

    const int q = lane >> 4;
    #pragma unroll
    for (int m = 0; m < 4; ++m)
        #pragma unroll
        for (int n = 0; n < 4; ++n) {
            const int col = w * 64 + n * 16 + arow;
            const float bv = eb1[e * DHID + col];
            #pragma unroll
            for (int j = 0; j < 4; ++j) {
                const int rr = m * 16 + q * 4 + j;
                if (rr < nrow) {   // padded rows alias real ehbuf rows with a different swizzle key -> must skip
                    const size_t d = (size_t)s_pair[rr] * DHID
                                   + (col & 0xE0) + ((col & 31) ^ (((rr >> 1) & 3) * 8));
                    ehbuf[d] = f2h(gelu_f(acc[m][n][j] + bv));
                }
            }
        }
}

// ---------- Kernel 3b: expert GEMM2 -> fp32 atomic accumulate into out ----------
__global__ __launch_bounds__(256) void k_e2(
    const unsigned short* __restrict__ ehbuf,
    const unsigned short* __restrict__ eW2T, const float* __restrict__ eb2,
    const float* __restrict__ alpha_p,
    const int* __restrict__ counts, const int* __restrict__ list_tok,
    const float* __restrict__ list_w, const int* __restrict__ list_slot,
    float* __restrict__ out)
{
    __shared__ unsigned short sA[3][64 * 32];
    __shared__ unsigned short sB[3][256 * 32];
    __shared__ int s_pair[64];
    __shared__ int s_tk[64];
    __shared__ float s_w[64];

    const int e = blockIdx.y;
    const int cnt = counts[e];
    const int base = blockIdx.x * 64;
    if (base >= cnt) return;
    const int ch = blockIdx.z;
    const int nrow = min(64, cnt - base);
    const int tid = threadIdx.x, lane = tid & 63, w = tid >> 6;

    if (tid < 64) {
        const int src = base + ((tid < nrow) ? tid : (nrow - 1));
        const int tok = list_tok[(size_t)e * T_TOKENS + src];
        s_tk[tid] = tok;
        s_pair[tid] = tok * 2 + list_slot[(size_t)e * T_TOKENS + src];
        s_w[tid] = (tid < nrow) ? list_w[(size_t)e * T_TOKENS + base + tid] : 0.f;
    }
    __syncthreads();

    const int srow = w * 16 + (lane >> 2);
    const unsigned short* gA = ehbuf + (size_t)s_pair[srow] * DHID + (lane & 3) * 8;
    const int sgr = (lane & 3) * 8;
    const unsigned short* gB[4];
    #pragma unroll
    for (int i = 0; i < 4; ++i)
        gB[i] = eW2T + (size_t)e * DMODEL * DHID
              + (size_t)(ch * 256 + w * 64 + i * 16 + (lane >> 2)) * DHID + sgr;

    const int arow = lane & 15, koff = (lane >> 4) * 8;
    const int q8r = ((arow >> 1) & 3) * 8;
    int aoff[4], boff[4];
    #pragma unroll
    for (int m = 0; m < 4; ++m) aoff[m] = (m * 16 + arow) * 32 + (koff ^ q8r);
    #pragma unroll
    for (int n = 0; n < 4; ++n) boff[n] = (w * 64 + n * 16 + arow) * 32 + (koff ^ q8r);

    f32x4 acc[4][4];
    #pragma unroll
    for (int m = 0; m < 4; ++m)
        #pragma unroll
        for (int n = 0; n < 4; ++n) { acc[m][n].x = 0.f; acc[m][n].y = 0.f; acc[m][n].z = 0.f; acc[m][n].w = 0.f; }

    auto STAGE = [&](int b, int kt) {
        const int kk = kt * 32;
        gl_lds16(gA + kk, &sA[b][w * 512]);
        #pragma unroll
        for (int i = 0; i < 4; ++i) gl_lds16(gB[i] + kk, &sB[b][w * 2048 + i * 512]);
    };

    STAGE(0, 0);
    STAGE(1, 1);
    for (int kt = 0; kt < 8; ++kt) {
        const int slot = kt % 3;
        if (kt + 2 < 8) { STAGE((kt + 2) % 3, kt + 2); WAIT_VM(10); }
        else if (kt + 1 < 8) { WAIT_VM(5); }
        else { WAIT_VM(0); }
        __builtin_amdgcn_s_barrier();
        __builtin_amdgcn_sched_barrier(0);
        f16x8 a[4];
        #pragma unroll
        for (int m = 0; m < 4; ++m) a[m] = *(const f16x8*)&sA[slot][aoff[m]];
        #pragma unroll
        for (int n = 0; n < 4; ++n) {
            f16x8 b = *(const f16x8*)&sB[slot][boff[n]];
            #pragma unroll
            for (int m = 0; m < 4; ++m) acc[m][n] = MFMA16F(a[m], b, acc[m][n]);
        }
        __builtin_amdgcn_s_barrier();
    }

    const float alpha = alpha_p[0];
    const int q = lane >> 4;
    #pragma unroll
    for (int m = 0; m < 4; ++m)
        #pragma unroll
        for (int n = 0; n < 4; ++n) {
            const int col = ch * 256 + w * 64 + n * 16 + arow;
            const float b2v = eb2[e * DMODEL + col];
            #pragma unroll
            for (int j = 0; j < 4; ++j) {
                const int r = m * 16 + q * 4 + j;
                if (r < nrow)
                    atomicAdd(out + (size_t)s_tk[r] * DMODEL + col,
                              s_w[r] * alpha * (acc[m][n][j] + b2v));
            }
        }
}

// ---------- launch ----------
extern "C" void kernel_launch(void* const* d_in, const int* in_sizes, int n_in,
                              void* d_out, int out_size, void* d_ws, size_t ws_size,
                              hipStream_t stream) {
    const float* hidden = (const float*)d_in[0];
    const float* feat   = (const float*)d_in[1];
    const float* ln_g   = (const float*)d_in[2];
    const float* ln_b   = (const float*)d_in[3];
    const float* stageW = (const float*)d_in[4];
    const float* stageb = (const float*)d_in[5];
    const float* gfW    = (const float*)d_in[6];
    const float* gfb    = (const float*)d_in[7];
    const float* psW1   = (const float*)d_in[8];
    const float* psb1   = (const float*)d_in[9];
    const float* psW2   = (const float*)d_in[10];
    const float* psb2   = (const float*)d_in[11];
    const float* irW1   = (const float*)d_in[12];
    const float* irb1   = (const float*)d_in[13];
    const float* irW2   = (const float*)d_in[14];
    const float* irb2   = (const float*)d_in[15];
    const float* eW1    = (const float*)d_in[16];
    const float* eb1    = (const float*)d_in[17];
    const float* eW2    = (const float*)d_in[18];
    const float* eb2    = (const float*)d_in[19];
    const float* alpha  = (const float*)d_in[20];

    float* out = (float*)d_out;

    char* p = (char*)d_ws;
    unsigned short* Ahi = (unsigned short*)p; p += (size_t)T_TOKENS * RIN * 2;
    unsigned short* Bhi = (unsigned short*)p; p += (size_t)2048 * RIN * 2;
    unsigned short* eW1T = (unsigned short*)p; p += (size_t)NE * DHID * DMODEL * 2;
    unsigned short* eW2T = (unsigned short*)p; p += (size_t)NE * DMODEL * DHID * 2;
    unsigned short* ehbuf = (unsigned short*)p; p += (size_t)T_TOKENS * 2 * DHID * 2;
    float* Dps = (float*)p;   p += (size_t)NG * 64 * DRH * 4;
    float* Cir = (float*)p;   p += (size_t)NG * 8 * DRH * 4;
    float* fbps = (float*)p;  p += (size_t)NG * DRH * 4;
    float* fbir = (float*)p;  p += (size_t)NG * DRH * 4;
    float* glog_buf = (float*)p; p += (size_t)T_TOKENS * NG * 4;
    float* ilog_buf = (float*)p; p += (size_t)T_TOKENS * NG * NES * 4;
    int* counts = (int*)p;    p += 128;
    int* nfix = counts + 16;
    int* fix_list = (int*)p;  p += (size_t)T_TOKENS * 4;
    int* list_tok = (int*)p;  p += (size_t)NE * T_TOKENS * 4;
    float* list_w = (float*)p; p += (size_t)NE * T_TOKENS * 4;
    int* list_slot = (int*)p; p += (size_t)NE * T_TOKENS * 4;

    k_mega1<<<MG_TOTAL, 256, 0, stream>>>(
        hidden, feat, ln_g, ln_b, Ahi, counts,
        stageW, stageb, psW1, psb1, Dps, fbps,
        gfW, gfb, irW1, irb1, Cir, fbir,
        Bhi, eW1, eW2, eW1T, eW2T, out);

    k_mega2<<<72, 256, 0, stream>>>(Dps, Cir, Bhi);

    k_rgemm<<<dim3(T_TOKENS / 128, 16), 512, 0, stream>>>(
        Ahi, Bhi, fbps, psW2, psb2, fbir, irW2, irb2, glog_buf, ilog_buf);

    hg_finalize2<<<T_TOKENS / 256, 256, 0, stream>>>(
        glog_buf, ilog_buf, counts, nfix, fix_list, list_tok, list_w, list_slot);

    hg_fixup<<<1024, 256, 0, stream>>>(
        hidden, feat, ln_g, ln_b, stageW, stageb, gfW, gfb,
        psW1, psb1, psW2, psb2, irW1, irb1, irW2, irb2,
        nfix, fix_list, counts, list_tok, list_w, list_slot);

    k_e1<<<dim3(T_TOKENS / 64, NE), 256, 0, stream>>>(
        Ahi, eW1T, eb1, counts, list_tok, list_slot, ehbuf);

    k_e2<<<dim3(T_TOKENS / 64, NE, 2), 256, 0, stream>>>(
        ehbuf, eW2T, eb2, alpha, counts, list_tok, list_w, list_slot, out);
}

// Round 24
// 333.053 us; speedup vs baseline: 1.0482x; 1.0482x over previous
//
#include <hip/hip_runtime.h>
#include <hip/hip_bf16.h>

#define T_TOKENS 16384
#define DMODEL 512
#define FFEAT 64
#define DFEMB 64
#define RIN 576
#define DRH 128
#define NG 8
#define NES 2
#define NE 16
#define DHID 256

typedef float f32x4 __attribute__((ext_vector_type(4)));
typedef _Float16 f16x8 __attribute__((ext_vector_type(8)));
#define MFMA16F(a, b, c) __builtin_amdgcn_mfma_f32_16x16x32_f16((a), (b), (c), 0, 0, 0)
#define WAIT_VM(N) asm volatile("s_waitcnt vmcnt(" #N ")" ::: "memory")

__device__ __forceinline__ float gelu_f(float x) {
    return 0.5f * x * (1.0f + erff(x * 0.7071067811865476f));
}
__device__ __forceinline__ unsigned short f2h(float x) {
    _Float16 h = (_Float16)x;
    union { _Float16 f; unsigned short u; } v; v.f = h;
    return v.u;
}
__device__ __forceinline__ float h2f(unsigned short u) {
    union { unsigned short u; _Float16 f; } v; v.u = u;
    return (float)v.f;
}
__device__ __forceinline__ void gl_lds16(const unsigned short* g, unsigned short* l) {
    __builtin_amdgcn_global_load_lds(
        (const __attribute__((address_space(1))) unsigned int*)g,
        (__attribute__((address_space(3))) unsigned int*)l, 16, 0, 0);
}

// ---------- Mega kernel 1: independent front-end jobs (expert transposes moved to k_rgemm) ----------
// job ranges (block id): [0,4096) prep | [.., +264) fold_ps | [.., +40) fold_ir
//                        | [.., +1024) bsplitT2 (psW1/irW1)
#define MG_PREP 4096
#define MG_FPS  264
#define MG_FIR  40
#define MG_T2   1024
#define MG_TOTAL (MG_PREP + MG_FPS + MG_FIR + MG_T2)

__global__ __launch_bounds__(256) void k_mega1(
    const float* __restrict__ hidden, const float* __restrict__ feat,
    const float* __restrict__ lng, const float* __restrict__ lnb,
    unsigned short* __restrict__ Ahi, int* __restrict__ cz,
    const float* __restrict__ stageW, const float* __restrict__ stageb,
    const float* __restrict__ psW1, const float* __restrict__ psb1,
    float* __restrict__ Dps, float* __restrict__ fbps,
    const float* __restrict__ gfW, const float* __restrict__ gfb,
    const float* __restrict__ irW1, const float* __restrict__ irb1,
    float* __restrict__ Cir, float* __restrict__ fbir,
    unsigned short* __restrict__ Bhi)
{
    __shared__ float s_t[32][33];
    int bid = blockIdx.x;
    const int tid = threadIdx.x;

    if (bid < MG_PREP) {
        // ---- prep: LN + fp16 swizzled A (+ zero routing counters) ----
        if (bid == 0 && tid < 32) cz[tid] = 0;  // counts[16]+nfix+pad
        const int t = bid * 4 + (tid >> 6);
        const int lane = tid & 63;
        const float* row = hidden + (size_t)t * DMODEL;
        float4 v0 = ((const float4*)row)[lane * 2 + 0];
        float4 v1 = ((const float4*)row)[lane * 2 + 1];
        float s = v0.x + v0.y + v0.z + v0.w + v1.x + v1.y + v1.z + v1.w;
        #pragma unroll
        for (int m = 1; m < 64; m <<= 1) s += __shfl_xor(s, m);
        const float mu = s * (1.0f / DMODEL);
        float sq = 0.f;
        { float d;
          d = v0.x - mu; sq += d * d; d = v0.y - mu; sq += d * d;
          d = v0.z - mu; sq += d * d; d = v0.w - mu; sq += d * d;
          d = v1.x - mu; sq += d * d; d = v1.y - mu; sq += d * d;
          d = v1.z - mu; sq += d * d; d = v1.w - mu; sq += d * d; }
        #pragma unroll
        for (int m = 1; m < 64; m <<= 1) sq += __shfl_xor(sq, m);
        const float rstd = rsqrtf(sq * (1.0f / DMODEL) + 1e-5f);
        float4 g0 = ((const float4*)lng)[lane * 2 + 0];
        float4 g1 = ((const float4*)lng)[lane * 2 + 1];
        float4 b0 = ((const float4*)lnb)[lane * 2 + 0];
        float4 b1 = ((const float4*)lnb)[lane * 2 + 1];
        float h[8];
        h[0] = (v0.x - mu) * rstd * g0.x + b0.x;
        h[1] = (v0.y - mu) * rstd * g0.y + b0.y;
        h[2] = (v0.z - mu) * rstd * g0.z + b0.z;
        h[3] = (v0.w - mu) * rstd * g0.w + b0.w;
        h[4] = (v1.x - mu) * rstd * g1.x + b1.x;
        h[5] = (v1.y - mu) * rstd * g1.y + b1.y;
        h[6] = (v1.z - mu) * rstd * g1.z + b1.z;
        h[7] = (v1.w - mu) * rstd * g1.w + b1.w;
        const int q8 = ((t >> 1) & 3) * 8;
        ushort4 H0, H1;
        H0.x = f2h(h[0]); H0.y = f2h(h[1]); H0.z = f2h(h[2]); H0.w = f2h(h[3]);
        H1.x = f2h(h[4]); H1.y = f2h(h[5]); H1.z = f2h(h[6]); H1.w = f2h(h[7]);
        unsigned short* pa = Ahi + (size_t)t * RIN;
        const int dst = (lane >> 2) * 32 + (((lane & 3) * 8) ^ q8);
        *(ushort4*)&pa[dst] = H0;  *(ushort4*)&pa[dst + 4] = H1;
        const float fv = feat[(size_t)t * FFEAT + lane];
        const int fd = DMODEL + (lane & 32) + ((lane & 31) ^ q8);
        pa[fd] = f2h(fv);
        return;
    }
    bid -= MG_PREP;

    if (bid < MG_FPS) {
        // ---- fold_ps: 2 f-slots per 256-thread block ----
        const int g = bid / 33;
        const int f = (bid % 33) * 2 + (tid >> 7);
        const int c = tid & 127;
        const float* Wt = psW1 + (size_t)g * RIN * DRH + (size_t)DMODEL * DRH;
        float acc = 0.f;
        if (f < 64) {
            for (int j = 0; j < DFEMB; ++j) acc = fmaf(stageW[f * DFEMB + j], Wt[(size_t)j * DRH + c], acc);
            Dps[((size_t)g * 64 + f) * DRH + c] = acc;
        } else if (f == 64) {
            for (int j = 0; j < DFEMB; ++j) acc = fmaf(stageb[j], Wt[(size_t)j * DRH + c], acc);
            fbps[g * DRH + c] = acc + psb1[g * DRH + c];
        }
        return;
    }
    bid -= MG_FPS;

    if (bid < MG_FIR) {
        // ---- fold_ir: 2 f-slots per 256-thread block ----
        const int g = bid / 5;
        const int f = (bid % 5) * 2 + (tid >> 7);
        const int c = tid & 127;
        const float* Wt = irW1 + (size_t)g * RIN * DRH + (size_t)DMODEL * DRH;
        float acc = 0.f;
        if (f < 8) {
            for (int j = 0; j < DFEMB; ++j) acc = fmaf(gfW[(size_t)(g * 8 + f) * DFEMB + j], Wt[(size_t)j * DRH + c], acc);
            Cir[((size_t)g * 8 + f) * DRH + c] = acc;
        } else if (f == 8) {
            for (int j = 0; j < DFEMB; ++j) acc = fmaf(gfb[g * DFEMB + j], Wt[(size_t)j * DRH + c], acc);
            fbir[g * DRH + c] = acc + irb1[g * DRH + c];
        }
        return;
    }
    bid -= MG_FIR;

    {
        // ---- router main-weight transpose: z=0 psW1, z=1 irW1 ----
        const int x = bid % 64, y = (bid / 64) % 8, z = bid / 512;
        const float* in = z ? irW1 : psW1;
        unsigned short* outHi = Bhi + (z ? (size_t)1024 * RIN : 0);
        const int tilesN = DRH >> 5;
        const int ko = (x / tilesN) << 5;
        const int no = (x % tilesN) << 5;
        const int r = tid >> 3, c0 = (tid & 7) * 4;
        {
            float4 v = *(const float4*)(in + (size_t)y * RIN * DRH + (size_t)(ko + r) * DRH + no + c0);
            s_t[r][c0] = v.x; s_t[r][c0 + 1] = v.y; s_t[r][c0 + 2] = v.z; s_t[r][c0 + 3] = v.w;
        }
        __syncthreads();
        float vv[4];
        #pragma unroll
        for (int j = 0; j < 4; ++j) vv[j] = s_t[c0 + j][r];
        const int col = no + r;
        const int q8 = ((col >> 1) & 3) * 8;
        ushort4 hi;
        hi.x = f2h(vv[0]); hi.y = f2h(vv[1]); hi.z = f2h(vv[2]); hi.w = f2h(vv[3]);
        *(ushort4*)(outHi + (size_t)y * DRH * RIN + (size_t)col * RIN + ko + (c0 ^ q8)) = hi;
    }
}

// ---------- Mega kernel 2: fold-dependent jobs (Dps transpose + ir tail) ----------
// [0,64) bsplitT(Dps -> Bhi rows 512.., kOff=512) | [64,72) irtail
__global__ __launch_bounds__(256) void k_mega2(
    const float* __restrict__ Dps, const float* __restrict__ Cir,
    unsigned short* __restrict__ Bhi)
{
    __shared__ float s_t[32][33];
    int bid = blockIdx.x;
    const int tid = threadIdx.x;

    if (bid < 64) {
        const int x = bid % 8, b = bid / 8;
        const int tilesN = DRH >> 5;
        const int ko = (x / tilesN) << 5;
        const int no = (x % tilesN) << 5;
        const int r = tid >> 3, c0 = (tid & 7) * 4;
        {
            float4 v = *(const float4*)(Dps + (size_t)b * 64 * DRH + (size_t)(ko + r) * DRH + no + c0);
            s_t[r][c0] = v.x; s_t[r][c0 + 1] = v.y; s_t[r][c0 + 2] = v.z; s_t[r][c0 + 3] = v.w;
        }
        __syncthreads();
        float vv[4];
        #pragma unroll
        for (int j = 0; j < 4; ++j) vv[j] = s_t[c0 + j][r];
        const int col = no + r;
        const int q8 = ((col >> 1) & 3) * 8;
        ushort4 hi;
        hi.x = f2h(vv[0]); hi.y = f2h(vv[1]); hi.z = f2h(vv[2]); hi.w = f2h(vv[3]);
        *(ushort4*)(Bhi + (size_t)b * DRH * RIN + (size_t)col * RIN + 512 + ko + (c0 ^ q8)) = hi;
        return;
    }
    bid -= 64;

    {
        const int g = bid;
        const int c = tid & 127;
        const int h = tid >> 7;
        const int col = 1024 + g * DRH + c;
        const int q8 = ((col >> 1) & 3) * 8;
        unsigned short* ph = Bhi + (size_t)col * RIN + DMODEL;
        for (int f = h * 32; f < h * 32 + 32; ++f) {
            float v = ((f >> 3) == g) ? Cir[((size_t)g * 8 + (f & 7)) * DRH + c] : 0.f;
            const int d = (f & 32) + ((f & 31) ^ q8);
            ph[d] = f2h(v);
        }
    }
}

// ---------- Kernel 2: router GEMM (R13 verified) + expert-weight transpose panel ----------
// grid (T/128, 17): bn<16 = GEMM column panels; bn==16 = eW1/eW2 transpose job
// (k_rgemm does NOT read eW1T/eW2T; only k_e1/k_e2 - launched after - do).
__global__ __launch_bounds__(512) void k_rgemm(
    const unsigned short* __restrict__ Ahi, const unsigned short* __restrict__ Bhi,
    const float* __restrict__ fbps, const float* __restrict__ psW2, const float* __restrict__ psb2,
    const float* __restrict__ fbir, const float* __restrict__ irW2, const float* __restrict__ irb2,
    float* __restrict__ glog, float* __restrict__ ilog,
    const float* __restrict__ eW1, const float* __restrict__ eW2,
    unsigned short* __restrict__ eW1T, unsigned short* __restrict__ eW2T)
{
    __shared__ unsigned short sAh[3][128 * 32];
    __shared__ unsigned short sBh[3][128 * 32];
    __shared__ float s_red[2][4][64][2];

    const int tid = threadIdx.x, lane = tid & 63, w = tid >> 6;
    const int t0 = blockIdx.x * 128, bn = blockIdx.y;

    if (bn == 16) {
        // ---- expert weight transpose: 4096 tiles over 128 blocks x 2 halves x 16 iters ----
        // tile decode identical to the former mega1 TE job: x=tile%128, y=(tile/128)%16, z=tile/2048
        const int half = tid >> 8;        // 0,1
        const int t256 = tid & 255;
        float (*st)[33] = (float(*)[33])((float*)&sAh[0][0] + half * 32 * 33);
        const long BS = (long)DMODEL * DHID;
        const int r = t256 >> 3, c0 = (t256 & 7) * 4;
        for (int it = 0; it < 16; ++it) {
            const int tile = blockIdx.x * 32 + it * 2 + half;
            const int x = tile & 127, y = (tile >> 7) & 15, z = tile >> 11;
            const int K = z ? DHID : DMODEL;
            const int N = z ? DMODEL : DHID;
            const float* in = z ? eW2 : eW1;
            unsigned short* outHi = z ? eW2T : eW1T;
            const int tilesN = N >> 5;
            const int ko = (x / tilesN) << 5;
            const int no = (x % tilesN) << 5;
            {
                float4 v = *(const float4*)(in + (size_t)y * BS + (size_t)(ko + r) * N + no + c0);
                st[r][c0] = v.x; st[r][c0 + 1] = v.y; st[r][c0 + 2] = v.z; st[r][c0 + 3] = v.w;
            }
            __syncthreads();
            float vv[4];
            #pragma unroll
            for (int j = 0; j < 4; ++j) vv[j] = st[c0 + j][r];
            const int col = no + r;
            const int q8 = ((col >> 1) & 3) * 8;
            ushort4 hi;
            hi.x = f2h(vv[0]); hi.y = f2h(vv[1]); hi.z = f2h(vv[2]); hi.w = f2h(vv[3]);
            *(ushort4*)(outHi + (size_t)y * BS + (size_t)col * K + ko + (c0 ^ q8)) = hi;
            __syncthreads();
        }
        return;
    }

    const int wm = w >> 2, wn = w & 3;
    const int arow = lane & 15, koff = (lane >> 4) * 8;
    const int q8r = ((arow >> 1) & 3) * 8;

    int aoff[4], boff[2];
    #pragma unroll
    for (int m = 0; m < 4; ++m) aoff[m] = (wm * 64 + m * 16 + arow) * 32 + (koff ^ q8r);
    #pragma unroll
    for (int n = 0; n < 2; ++n) boff[n] = (wn * 32 + n * 16 + arow) * 32 + (koff ^ q8r);

    const int srow = w * 16 + (lane >> 2);
    const int sgr = (lane & 3) * 8;
    const unsigned short* gAh = Ahi + (size_t)(t0 + srow) * RIN + sgr;
    const unsigned short* gBh = Bhi + (size_t)(bn * 128 + srow) * RIN + sgr;

    f32x4 acc[4][2];
    #pragma unroll
    for (int m = 0; m < 4; ++m)
        #pragma unroll
        for (int n = 0; n < 2; ++n) { acc[m][n].x = 0.f; acc[m][n].y = 0.f; acc[m][n].z = 0.f; acc[m][n].w = 0.f; }

    auto STAGE = [&](int b, int kt) {
        const int kk = kt * 32;
        gl_lds16(gAh + kk, &sAh[b][w * 512]);
        gl_lds16(gBh + kk, &sBh[b][w * 512]);
    };

    STAGE(0, 0);
    STAGE(1, 1);
    for (int kt = 0; kt < 18; ++kt) {
        const int slot = kt % 3;
        if (kt + 2 < 18) { STAGE((kt + 2) % 3, kt + 2); WAIT_VM(4); }
        else if (kt + 1 < 18) { WAIT_VM(2); }
        else { WAIT_VM(0); }
        __builtin_amdgcn_s_barrier();
        __builtin_amdgcn_sched_barrier(0);
        f16x8 ah[4];
        #pragma unroll
        for (int m = 0; m < 4; ++m) ah[m] = *(const f16x8*)&sAh[slot][aoff[m]];
        #pragma unroll
        for (int n = 0; n < 2; ++n) {
            f16x8 b = *(const f16x8*)&sBh[slot][boff[n]];
            #pragma unroll
            for (int m = 0; m < 4; ++m) acc[m][n] = MFMA16F(ah[m], b, acc[m][n]);
        }
        __builtin_amdgcn_s_barrier();
    }

    // fused second layer (one group per block)
    const bool isPS = (bn < 8);
    const int g = bn & 7;
    const int q = lane >> 4;
    if (isPS) {
        float r0[4][4] = {};
        #pragma unroll
        for (int n = 0; n < 2; ++n) {
            const int cg = wn * 32 + n * 16 + arow;
            const float b1 = fbps[g * DRH + cg];
            const float w2 = psW2[g * DRH + cg];
            #pragma unroll
            for (int m = 0; m < 4; ++m)
                #pragma unroll
                for (int j = 0; j < 4; ++j)
                    r0[m][j] += gelu_f(acc[m][n][j] + b1) * w2;
        }
        #pragma unroll
        for (int mk = 1; mk < 16; mk <<= 1)
            #pragma unroll
            for (int m = 0; m < 4; ++m)
                #pragma unroll
                for (int j = 0; j < 4; ++j) r0[m][j] += __shfl_xor(r0[m][j], mk);
        if (arow == 0) {
            #pragma unroll
            for (int m = 0; m < 4; ++m)
                #pragma unroll
                for (int j = 0; j < 4; ++j) {
                    s_red[wm][wn][m * 16 + q * 4 + j][0] = r0[m][j];
                }
        }
    } else {
        float r0[4][4] = {}, r1[4][4] = {};
        #pragma unroll
        for (int n = 0; n < 2; ++n) {
            const int cg = wn * 32 + n * 16 + arow;
            const float b1 = fbir[g * DRH + cg];
            const float w20 = irW2[(size_t)(g * DRH + cg) * NES + 0];
            const float w21 = irW2[(size_t)(g * DRH + cg) * NES + 1];
            #pragma unroll
            for (int m = 0; m < 4; ++m)
                #pragma unroll
                for (int j = 0; j < 4; ++j) {
                    const float v = gelu_f(acc[m][n][j] + b1);
                    r0[m][j] = fmaf(v, w20, r0[m][j]);
                    r1[m][j] = fmaf(v, w21, r1[m][j]);
                }
        }
        #pragma unroll
        for (int mk = 1; mk < 16; mk <<= 1)
            #pragma unroll
            for (int m = 0; m < 4; ++m)
                #pragma unroll
                for (int j = 0; j < 4; ++j) {
                    r0[m][j] += __shfl_xor(r0[m][j], mk);
                    r1[m][j] += __shfl_xor(r1[m][j], mk);
                }
        if (arow == 0) {
            #pragma unroll
            for (int m = 0; m < 4; ++m)
                #pragma unroll
                for (int j = 0; j < 4; ++j) {
                    s_red[wm][wn][m * 16 + q * 4 + j][0] = r0[m][j];
                    s_red[wm][wn][m * 16 + q * 4 + j][1] = r1[m][j];
                }
        }
    }
    __syncthreads();
    if (tid < 128) {
        const int row = tid;
        const int wmm = row >> 6, rl = row & 63;
        if (isPS) {
            float v0 = s_red[wmm][0][rl][0] + s_red[wmm][1][rl][0]
                     + s_red[wmm][2][rl][0] + s_red[wmm][3][rl][0];
            glog[(size_t)(t0 + row) * NG + g] = v0 + psb2[g];
        } else {
            float v0 = s_red[wmm][0][rl][0] + s_red[wmm][1][rl][0]
                     + s_red[wmm][2][rl][0] + s_red[wmm][3][rl][0];
            float v1 = s_red[wmm][0][rl][1] + s_red[wmm][1][rl][1]
                     + s_red[wmm][2][rl][1] + s_red[wmm][3][rl][1];
            const size_t bidx = ((size_t)(t0 + row) * NG + g) * NES;
            ilog[bidx + 0] = v0 + irb2[g * NES + 0];
            ilog[bidx + 1] = v1 + irb2[g * NES + 1];
        }
    }
}

// ---------- Kernel 2b: finalize, block-aggregated atomics ----------
#define MARGIN 4e-3f
__global__ __launch_bounds__(256) void hg_finalize2(
    const float* __restrict__ glog_buf, const float* __restrict__ ilog_buf,
    int* __restrict__ counts, int* __restrict__ nfix, int* __restrict__ fix_list,
    int* __restrict__ list_tok, float* __restrict__ list_w, int* __restrict__ list_slot)
{
    __shared__ int s_cnt[NE];
    __shared__ int s_base[NE];
    __shared__ int s_fcnt, s_fbase;

    const int tid = threadIdx.x;
    const int t = blockIdx.x * 256 + tid;
    if (tid < NE) s_cnt[tid] = 0;
    if (tid == 0) s_fcnt = 0;
    __syncthreads();

    float gl[NG];
    *(float4*)&gl[0] = ((const float4*)(glog_buf + (size_t)t * NG))[0];
    *(float4*)&gl[4] = ((const float4*)(glog_buf + (size_t)t * NG))[1];
    int i1 = 0; float m1 = gl[0];
    #pragma unroll
    for (int g = 1; g < NG; ++g) if (gl[g] > m1) { m1 = gl[g]; i1 = g; }
    int i2 = -1; float m2 = -3.4e38f;
    #pragma unroll
    for (int g = 0; g < NG; ++g) if (g != i1 && gl[g] > m2) { m2 = gl[g]; i2 = g; }
    float m3 = -3.4e38f;
    #pragma unroll
    for (int g = 0; g < NG; ++g) if (g != i1 && g != i2 && gl[g] > m3) m3 = gl[g];

    const float ila0 = ilog_buf[((size_t)t * NG + i1) * NES + 0];
    const float ila1 = ilog_buf[((size_t)t * NG + i1) * NES + 1];
    const float ilb0 = ilog_buf[((size_t)t * NG + i2) * NES + 0];
    const float ilb1 = ilog_buf[((size_t)t * NG + i2) * NES + 1];

    const bool flag = ((m2 - m3) < MARGIN) || (fabsf(ila1 - ila0) < MARGIN)
                   || (fabsf(ilb1 - ilb0) < MARGIN);

    const float ex = expf(m2 - m1);
    const float inv = 1.0f / (1.0f + ex);
    const int   gsel[2] = {i1, i2};
    const float wsel[2] = {inv, ex * inv};
    const int   ksel[2] = {(ila1 > ila0) ? 1 : 0, (ilb1 > ilb0) ? 1 : 0};

    int eid[2] = {0, 0}, lo[2] = {0, 0}, fo = 0;
    if (!flag) {
        #pragma unroll
        for (int s = 0; s < 2; ++s) {
            eid[s] = gsel[s] * NES + ksel[s];
            lo[s] = atomicAdd(&s_cnt[eid[s]], 1);
        }
    } else {
        fo = atomicAdd(&s_fcnt, 1);
    }
    __syncthreads();
    if (tid < NE) s_base[tid] = atomicAdd(&counts[tid], s_cnt[tid]);
    if (tid == 16) s_fbase = atomicAdd(nfix, s_fcnt);
    __syncthreads();

    if (!flag) {
        #pragma unroll
        for (int s = 0; s < 2; ++s) {
            const int pos = s_base[eid[s]] + lo[s];
            list_tok[(size_t)eid[s] * T_TOKENS + pos] = t;
            list_w[(size_t)eid[s] * T_TOKENS + pos] = wsel[s];
            list_slot[(size_t)eid[s] * T_TOKENS + pos] = s;
        }
    } else {
        fix_list[s_fbase + fo] = t;
    }
}

// ---------- Kernel 2c: exact fp32 fixup, 4-wave parallel, unrolled ----------
__global__ __launch_bounds__(256) void hg_fixup(
    const float* __restrict__ hidden, const float* __restrict__ feat,
    const float* __restrict__ lng, const float* __restrict__ lnb,
    const float* __restrict__ stageW, const float* __restrict__ stageb,
    const float* __restrict__ gfW, const float* __restrict__ gfb,
    const float* __restrict__ psW1, const float* __restrict__ psb1,
    const float* __restrict__ psW2, const float* __restrict__ psb2,
    const float* __restrict__ irW1, const float* __restrict__ irb1,
    const float* __restrict__ irW2, const float* __restrict__ irb2,
    const int* __restrict__ nfix, const int* __restrict__ fix_list,
    int* __restrict__ counts, int* __restrict__ list_tok, float* __restrict__ list_w,
    int* __restrict__ list_slot)
{
    __shared__ float s_rin[RIN];
    __shared__ float s_tail[2][DFEMB];
    __shared__ float s_gl[NG];
    __shared__ float s_part[4][2];
    __shared__ int s_sel[2];
    __shared__ float s_wsel[2];

    const int tid = threadIdx.x, lane = tid & 63, w = tid >> 6;
    const int nf = nfix[0];
    for (int idx = blockIdx.x; idx < nf; idx += gridDim.x) {
        const int t = fix_list[idx];
        if (w == 0) {
            const float* row = hidden + (size_t)t * DMODEL;
            float4 v0 = ((const float4*)row)[lane * 2 + 0];
            float4 v1 = ((const float4*)row)[lane * 2 + 1];
            float s = v0.x + v0.y + v0.z + v0.w + v1.x + v1.y + v1.z + v1.w;
            #pragma unroll
            for (int m = 1; m < 64; m <<= 1) s += __shfl_xor(s, m);
            const float mu = s * (1.0f / DMODEL);
            float sq = 0.f;
            { float d;
              d = v0.x - mu; sq += d * d; d = v0.y - mu; sq += d * d;
              d = v0.z - mu; sq += d * d; d = v0.w - mu; sq += d * d;
              d = v1.x - mu; sq += d * d; d = v1.y - mu; sq += d * d;
              d = v1.z - mu; sq += d * d; d = v1.w - mu; sq += d * d; }
            #pragma unroll
            for (int m = 1; m < 64; m <<= 1) sq += __shfl_xor(sq, m);
            const float rstd = rsqrtf(sq * (1.0f / DMODEL) + 1e-5f);
            float4 g0 = ((const float4*)lng)[lane * 2 + 0];
            float4 g1 = ((const float4*)lng)[lane * 2 + 1];
            float4 b0 = ((const float4*)lnb)[lane * 2 + 0];
            float4 b1 = ((const float4*)lnb)[lane * 2 + 1];
            s_rin[lane * 8 + 0] = (v0.x - mu) * rstd * g0.x + b0.x;
            s_rin[lane * 8 + 1] = (v0.y - mu) * rstd * g0.y + b0.y;
            s_rin[lane * 8 + 2] = (v0.z - mu) * rstd * g0.z + b0.z;
            s_rin[lane * 8 + 3] = (v0.w - mu) * rstd * g0.w + b0.w;
            s_rin[lane * 8 + 4] = (v1.x - mu) * rstd * g1.x + b1.x;
            s_rin[lane * 8 + 5] = (v1.y - mu) * rstd * g1.y + b1.y;
            s_rin[lane * 8 + 6] = (v1.z - mu) * rstd * g1.z + b1.z;
            s_rin[lane * 8 + 7] = (v1.w - mu) * rstd * g1.w + b1.w;
        } else if (w == 1) {
            float se = stageb[lane];
            #pragma unroll 8
            for (int f = 0; f < FFEAT; ++f)
                se = fmaf(feat[(size_t)t * FFEAT + f], stageW[f * DFEMB + lane], se);
            s_rin[DMODEL + lane] = se;
        }
        __syncthreads();

        #pragma unroll
        for (int gi = 0; gi < 2; ++gi) {
            const int g = w * 2 + gi;
            float a0 = psb1[g * DRH + lane];
            float a1 = psb1[g * DRH + 64 + lane];
            const float* W = psW1 + (size_t)g * RIN * DRH;
            #pragma unroll 8
            for (int k = 0; k < RIN; ++k) {
                const float r = s_rin[k];
                a0 = fmaf(r, W[(size_t)k * DRH + lane], a0);
                a1 = fmaf(r, W[(size_t)k * DRH + 64 + lane], a1);
            }
            float p = gelu_f(a0) * psW2[g * DRH + lane] + gelu_f(a1) * psW2[g * DRH + 64 + lane];
            #pragma unroll
            for (int m = 1; m < 64; m <<= 1) p += __shfl_xor(p, m);
            if (lane == 0) s_gl[g] = p + psb2[g];
        }
        __syncthreads();

        if (tid == 0) {
            int i1 = 0; float m1 = s_gl[0];
            #pragma unroll
            for (int g = 1; g < NG; ++g) if (s_gl[g] > m1) { m1 = s_gl[g]; i1 = g; }
            int i2 = -1; float m2 = -3.4e38f;
            #pragma unroll
            for (int g = 0; g < NG; ++g) if (g != i1 && s_gl[g] > m2) { m2 = s_gl[g]; i2 = g; }
            const float ex = expf(m2 - m1);
            const float inv = 1.0f / (1.0f + ex);
            s_sel[0] = i1; s_sel[1] = i2;
            s_wsel[0] = inv; s_wsel[1] = ex * inv;
        }
        __syncthreads();

        const int pr = w >> 1;
        const int gsel = s_sel[pr];
        if ((w & 1) == 0) {
            float ge = gfb[gsel * DFEMB + lane];
            #pragma unroll
            for (int f = 0; f < 8; ++f)
                ge = fmaf(feat[(size_t)t * FFEAT + gsel * 8 + f],
                          gfW[(size_t)(gsel * 8 + f) * DFEMB + lane], ge);
            s_tail[pr][lane] = ge;
        }
        __syncthreads();

        {
            const int col = (w & 1) * 64 + lane;
            float a = irb1[gsel * DRH + col];
            const float* W = irW1 + (size_t)gsel * RIN * DRH + col;
            #pragma unroll 8
            for (int k = 0; k < DMODEL; ++k)
                a = fmaf(s_rin[k], W[(size_t)k * DRH], a);
            #pragma unroll 8
            for (int k = 0; k < DFEMB; ++k)
                a = fmaf(s_tail[pr][k], W[(size_t)(DMODEL + k) * DRH], a);
            const float v = gelu_f(a);
            float e0 = v * irW2[(size_t)(gsel * DRH + col) * NES + 0];
            float e1 = v * irW2[(size_t)(gsel * DRH + col) * NES + 1];
            #pragma unroll
            for (int m = 1; m < 64; m <<= 1) {
                e0 += __shfl_xor(e0, m);
                e1 += __shfl_xor(e1, m);
            }
            if (lane == 0) { s_part[w][0] = e0; s_part[w][1] = e1; }
        }
        __syncthreads();

        if (tid == 0) {
            #pragma unroll
            for (int p2 = 0; p2 < 2; ++p2) {
                const float e0 = s_part[p2 * 2][0] + s_part[p2 * 2 + 1][0];
                const float e1 = s_part[p2 * 2][1] + s_part[p2 * 2 + 1][1];
                const int eid = s_sel[p2] * NES + ((e1 > e0) ? 1 : 0);
                const int pos = atomicAdd(&counts[eid], 1);
                list_tok[(size_t)eid * T_TOKENS + pos] = t;
                list_w[(size_t)eid * T_TOKENS + pos] = s_wsel[p2];
                list_slot[(size_t)eid * T_TOKENS + pos] = p2;
            }
        }
        __syncthreads();
    }
}

// ---------- Kernel 3a: expert GEMM1 -> ehbuf (depth-3 pipeline) ----------
__global__ __launch_bounds__(256) void k_e1(
    const unsigned short* __restrict__ Ahi,
    const unsigned short* __restrict__ eW1T, const float* __restrict__ eb1,
    const int* __restrict__ counts, const int* __restrict__ list_tok,
    const int* __restrict__ list_slot, unsigned short* __restrict__ ehbuf)
{
    __shared__ unsigned short sA[3][64 * 32];
    __shared__ unsigned short sB[3][256 * 32];
    __shared__ int s_tok[64];
    __shared__ int s_pair[64];

    const int e = blockIdx.y;
    const int cnt = counts[e];
    const int base = blockIdx.x * 64;
    if (base >= cnt) return;
    const int nrow = min(64, cnt - base);
    const int tid = threadIdx.x, lane = tid & 63, w = tid >> 6;

    if (tid < 64) {
        const int src = base + ((tid < nrow) ? tid : (nrow - 1));
        s_tok[tid] = list_tok[(size_t)e * T_TOKENS + src];
        s_pair[tid] = s_tok[tid] * 2 + list_slot[(size_t)e * T_TOKENS + src];
    }
    __syncthreads();

    const int srow = w * 16 + (lane >> 2);
    const int stok = s_tok[srow];
    const int qcor = ((srow >> 1) & 3) ^ ((stok >> 1) & 3);
    const unsigned short* gA = Ahi + (size_t)stok * RIN + 8 * ((lane & 3) ^ qcor);
    const int sgr = (lane & 3) * 8;
    const unsigned short* gB[4];
    #pragma unroll
    for (int i = 0; i < 4; ++i)
        gB[i] = eW1T + (size_t)e * DHID * DMODEL + (size_t)(w * 64 + i * 16 + (lane >> 2)) * DMODEL + sgr;

    const int arow = lane & 15, koff = (lane >> 4) * 8;
    const int q8r = ((arow >> 1) & 3) * 8;
    int aoff[4], boff[4];
    #pragma unroll
    for (int m = 0; m < 4; ++m) aoff[m] = (m * 16 + arow) * 32 + (koff ^ q8r);
    #pragma unroll
    for (int n = 0; n < 4; ++n) boff[n] = (w * 64 + n * 16 + arow) * 32 + (koff ^ q8r);

    f32x4 acc[4][4];
    #pragma unroll
    for (int m = 0; m < 4; ++m)
        #pragma unroll
        for (int n = 0; n < 4; ++n) { acc[m][n].x = 0.f; acc[m][n].y = 0.f; acc[m][n].z = 0.f; acc[m][n].w = 0.f; }

    auto STAGE = [&](int b, int kt) {
        const int kk = kt * 32;
        gl_lds16(gA + kk, &sA[b][w * 512]);
        #pragma unroll
        for (int i = 0; i < 4; ++i) gl_lds16(gB[i] + kk, &sB[b][w * 2048 + i * 512]);
    };

    STAGE(0, 0);
    STAGE(1, 1);
    for (int kt = 0; kt < 16; ++kt) {
        const int slot = kt % 3;
        if (kt + 2 < 16) { STAGE((kt + 2) % 3, kt + 2); WAIT_VM(10); }
        else if (kt + 1 < 16) { WAIT_VM(5); }
        else { WAIT_VM(0); }
        __builtin_amdgcn_s_barrier();
        __builtin_amdgcn_sched_barrier(0);
        f16x8 a[4];
        #pragma unroll
        for (int m = 0; m < 4; ++m) a[m] = *(const f16x8*)&sA[slot][aoff[m]];
        #pragma unroll
        for (int n = 0; n < 4; ++n) {
            f16x8 b = *(const f16x8*)&sB[slot][boff[n]];
            #pragma unroll
            for (int m = 0; m < 4; ++m) acc[m][n] = MFMA16F(a[m], b, acc[m][n]);
        }
        __builtin_amdgcn_s_barrier();
    }

    const int q = lane >> 4;
    #pragma unroll
    for (int m = 0; m < 4; ++m)
        #pragma unroll
        for (int n = 0; n < 4; ++n) {
            const int col = w * 64 + n * 16 + arow;
            const float bv = eb1[e * DHID + col];
            #pragma unroll
            for (int j = 0; j < 4; ++j) {
                const int rr = m * 16 + q * 4 + j;
                if (rr < nrow) {   // padded rows alias real ehbuf rows with a different swizzle key -> must skip
                    const size_t d = (size_t)s_pair[rr] * DHID
                                   + (col & 0xE0) + ((col & 31) ^ (((rr >> 1) & 3) * 8));
                    ehbuf[d] = f2h(gelu_f(acc[m][n][j] + bv));
                }
            }
        }
}

// ---------- Kernel 3b: expert GEMM2 -> contrib (depth-3 pipeline) ----------
__global__ __launch_bounds__(256) void k_e2(
    const unsigned short* __restrict__ ehbuf,
    const unsigned short* __restrict__ eW2T, const float* __restrict__ eb2,
    const float* __restrict__ alpha_p,
    const int* __restrict__ counts, const int* __restrict__ list_tok,
    const float* __restrict__ list_w, const int* __restrict__ list_slot,
    unsigned short* __restrict__ contrib)
{
    __shared__ unsigned short sA[3][64 * 32];
    __shared__ unsigned short sB[3][256 * 32];
    __shared__ int s_pair[64];
    __shared__ float s_w[64];

    const int e = blockIdx.y;
    const int cnt = counts[e];
    const int base = blockIdx.x * 64;
    if (base >= cnt) return;
    const int ch = blockIdx.z;
    const int nrow = min(64, cnt - base);
    const int tid = threadIdx.x, lane = tid & 63, w = tid >> 6;

    if (tid < 64) {
        const int src = base + ((tid < nrow) ? tid : (nrow - 1));
        const int tok = list_tok[(size_t)e * T_TOKENS + src];
        s_pair[tid] = tok * 2 + list_slot[(size_t)e * T_TOKENS + src];
        s_w[tid] = (tid < nrow) ? list_w[(size_t)e * T_TOKENS + base + tid] : 0.f;
    }
    __syncthreads();

    const int srow = w * 16 + (lane >> 2);
    const unsigned short* gA = ehbuf + (size_t)s_pair[srow] * DHID + (lane & 3) * 8;
    const int sgr = (lane & 3) * 8;
    const unsigned short* gB[4];
    #pragma unroll
    for (int i = 0; i < 4; ++i)
        gB[i] = eW2T + (size_t)e * DMODEL * DHID
              + (size_t)(ch * 256 + w * 64 + i * 16 + (lane >> 2)) * DHID + sgr;

    const int arow = lane & 15, koff = (lane >> 4) * 8;
    const int q8r = ((arow >> 1) & 3) * 8;
    int aoff[4], boff[4];
    #pragma unroll
    for (int m = 0; m < 4; ++m) aoff[m] = (m * 16 + arow) * 32 + (koff ^ q8r);
    #pragma unroll
    for (int n = 0; n < 4; ++n) boff[n] = (w * 64 + n * 16 + arow) * 32 + (koff ^ q8r);

    f32x4 acc[4][4];
    #pragma unroll
    for (int m = 0; m < 4; ++m)
        #pragma unroll
        for (int n = 0; n < 4; ++n) { acc[m][n].x = 0.f; acc[m][n].y = 0.f; acc[m][n].z = 0.f; acc[m][n].w = 0.f; }

    auto STAGE = [&](int b, int kt) {
        const int kk = kt * 32;
        gl_lds16(gA + kk, &sA[b][w * 512]);
        #pragma unroll
        for (int i = 0; i < 4; ++i) gl_lds16(gB[i] + kk, &sB[b][w * 2048 + i * 512]);
    };

    STAGE(0, 0);
    STAGE(1, 1);
    for (int kt = 0; kt < 8; ++kt) {
        const int slot = kt % 3;
        if (kt + 2 < 8) { STAGE((kt + 2) % 3, kt + 2); WAIT_VM(10); }
        else if (kt + 1 < 8) { WAIT_VM(5); }
        else { WAIT_VM(0); }
        __builtin_amdgcn_s_barrier();
        __builtin_amdgcn_sched_barrier(0);
        f16x8 a[4];
        #pragma unroll
        for (int m = 0; m < 4; ++m) a[m] = *(const f16x8*)&sA[slot][aoff[m]];
        #pragma unroll
        for (int n = 0; n < 4; ++n) {
            f16x8 b = *(const f16x8*)&sB[slot][boff[n]];
            #pragma unroll
            for (int m = 0; m < 4; ++m) acc[m][n] = MFMA16F(a[m], b, acc[m][n]);
        }
        __builtin_amdgcn_s_barrier();
    }

    const float alpha = alpha_p[0];
    const int q = lane >> 4;
    #pragma unroll
    for (int m = 0; m < 4; ++m)
        #pragma unroll
        for (int n = 0; n < 4; ++n) {
            const int col = ch * 256 + w * 64 + n * 16 + arow;
            const float b2v = eb2[e * DMODEL + col];
            #pragma unroll
            for (int j = 0; j < 4; ++j) {
                const int r = m * 16 + q * 4 + j;
                if (r < nrow)
                    contrib[(size_t)s_pair[r] * DMODEL + col] =
                        f2h(s_w[r] * alpha * (acc[m][n][j] + b2v));
            }
        }
}

// ---------- Kernel 4: combine out = hidden + c0 + c1 ----------
__global__ __launch_bounds__(256) void k_combine(
    const float* __restrict__ hidden, const unsigned short* __restrict__ contrib,
    float* __restrict__ out)
{
    const size_t gid = (size_t)blockIdx.x * 256 + threadIdx.x;
    const int t = (int)(gid >> 6);
    const int c = (int)(gid & 63) * 8;
    const float* hp = hidden + (size_t)t * DMODEL + c;
    float4 h0 = ((const float4*)hp)[0];
    float4 h1 = ((const float4*)hp)[1];
    const unsigned short* c0p = contrib + ((size_t)t * 2 + 0) * DMODEL + c;
    const unsigned short* c1p = contrib + ((size_t)t * 2 + 1) * DMODEL + c;
    ushort4 a0 = ((const ushort4*)c0p)[0], a1 = ((const ushort4*)c0p)[1];
    ushort4 b0 = ((const ushort4*)c1p)[0], b1 = ((const ushort4*)c1p)[1];
    float4 o0, o1;
    o0.x = h0.x + h2f(a0.x) + h2f(b0.x);
    o0.y = h0.y + h2f(a0.y) + h2f(b0.y);
    o0.z = h0.z + h2f(a0.z) + h2f(b0.z);
    o0.w = h0.w + h2f(a0.w) + h2f(b0.w);
    o1.x = h1.x + h2f(a1.x) + h2f(b1.x);
    o1.y = h1.y + h2f(a1.y) + h2f(b1.y);
    o1.z = h1.z + h2f(a1.z) + h2f(b1.z);
    o1.w = h1.w + h2f(a1.w) + h2f(b1.w);
    float* op = out + (size_t)t * DMODEL + c;
    ((float4*)op)[0] = o0;
    ((float4*)op)[1] = o1;
}

// ---------- launch ----------
extern "C" void kernel_launch(void* const* d_in, const int* in_sizes, int n_in,
                              void* d_out, int out_size, void* d_ws, size_t ws_size,
                              hipStream_t stream) {
    const float* hidden = (const float*)d_in[0];
    const float* feat   = (const float*)d_in[1];
    const float* ln_g   = (const float*)d_in[2];
    const float* ln_b   = (const float*)d_in[3];
    const float* stageW = (const float*)d_in[4];
    const float* stageb = (const float*)d_in[5];
    const float* gfW    = (const float*)d_in[6];
    const float* gfb    = (const float*)d_in[7];
    const float* psW1   = (const float*)d_in[8];
    const float* psb1   = (const float*)d_in[9];
    const float* psW2   = (const float*)d_in[10];
    const float* psb2   = (const float*)d_in[11];
    const float* irW1   = (const float*)d_in[12];
    const float* irb1   = (const float*)d_in[13];
    const float* irW2   = (const float*)d_in[14];
    const float* irb2   = (const float*)d_in[15];
    const float* eW1    = (const float*)d_in[16];
    const float* eb1    = (const float*)d_in[17];
    const float* eW2    = (const float*)d_in[18];
    const float* eb2    = (const float*)d_in[19];
    const float* alpha  = (const float*)d_in[20];

    float* out = (float*)d_out;

    char* p = (char*)d_ws;
    unsigned short* Ahi = (unsigned short*)p; p += (size_t)T_TOKENS * RIN * 2;
    unsigned short* Bhi = (unsigned short*)p; p += (size_t)2048 * RIN * 2;
    unsigned short* eW1T = (unsigned short*)p; p += (size_t)NE * DHID * DMODEL * 2;
    unsigned short* eW2T = (unsigned short*)p; p += (size_t)NE * DMODEL * DHID * 2;
    unsigned short* contrib = (unsigned short*)p; p += (size_t)T_TOKENS * 2 * DMODEL * 2;
    unsigned short* ehbuf = (unsigned short*)p; p += (size_t)T_TOKENS * 2 * DHID * 2;
    float* Dps = (float*)p;   p += (size_t)NG * 64 * DRH * 4;
    float* Cir = (float*)p;   p += (size_t)NG * 8 * DRH * 4;
    float* fbps = (float*)p;  p += (size_t)NG * DRH * 4;
    float* fbir = (float*)p;  p += (size_t)NG * DRH * 4;
    float* glog_buf = (float*)p; p += (size_t)T_TOKENS * NG * 4;
    float* ilog_buf = (float*)p; p += (size_t)T_TOKENS * NG * NES * 4;
    int* counts = (int*)p;    p += 128;
    int* nfix = counts + 16;
    int* fix_list = (int*)p;  p += (size_t)T_TOKENS * 4;
    int* list_tok = (int*)p;  p += (size_t)NE * T_TOKENS * 4;
    float* list_w = (float*)p; p += (size_t)NE * T_TOKENS * 4;
    int* list_slot = (int*)p; p += (size_t)NE * T_TOKENS * 4;

    k_mega1<<<MG_TOTAL, 256, 0, stream>>>(
        hidden, feat, ln_g, ln_b, Ahi, counts,
        stageW, stageb, psW1, psb1, Dps, fbps,
        gfW, gfb, irW1, irb1, Cir, fbir,
        Bhi);

    k_mega2<<<72, 256, 0, stream>>>(Dps, Cir, Bhi);

    k_rgemm<<<dim3(T_TOKENS / 128, 17), 512, 0, stream>>>(
        Ahi, Bhi, fbps, psW2, psb2, fbir, irW2, irb2, glog_buf, ilog_buf,
        eW1, eW2, eW1T, eW2T);

    hg_finalize2<<<T_TOKENS / 256, 256, 0, stream>>>(
        glog_buf, ilog_buf, counts, nfix, fix_list, list_tok, list_w, list_slot);

    hg_fixup<<<1024, 256, 0, stream>>>(
        hidden, feat, ln_g, ln_b, stageW, stageb, gfW, gfb,
        psW1, psb1, psW2, psb2, irW1, irb1, irW2, irb2,
        nfix, fix_list, counts, list_tok, list_w, list_slot);

    k_e1<<<dim3(T_TOKENS / 64, NE), 256, 0, stream>>>(
        Ahi, eW1T, eb1, counts, list_tok, list_slot, ehbuf);

    k_e2<<<dim3(T_TOKENS / 64, NE, 2), 256, 0, stream>>>(
        ehbuf, eW2T, eb2, alpha, counts, list_tok, list_w, list_slot, contrib);

    k_combine<<<(T_TOKENS * DMODEL / 8) / 256, 256, 0, stream>>>(hidden, contrib, out);
}

// Round 25
// 323.472 us; speedup vs baseline: 1.0793x; 1.0296x over previous
//
#include <hip/hip_runtime.h>
#include <hip/hip_bf16.h>

#define T_TOKENS 16384
#define DMODEL 512
#define FFEAT 64
#define DFEMB 64
#define RIN 576
#define DRH 128
#define NG 8
#define NES 2
#define NE 16
#define DHID 256

typedef float f32x4 __attribute__((ext_vector_type(4)));
typedef _Float16 f16x8 __attribute__((ext_vector_type(8)));
#define MFMA16F(a, b, c) __builtin_amdgcn_mfma_f32_16x16x32_f16((a), (b), (c), 0, 0, 0)
#define WAIT_VM(N) asm volatile("s_waitcnt vmcnt(" #N ")" ::: "memory")

__device__ __forceinline__ float gelu_f(float x) {
    return 0.5f * x * (1.0f + erff(x * 0.7071067811865476f));
}
__device__ __forceinline__ unsigned short f2h(float x) {
    _Float16 h = (_Float16)x;
    union { _Float16 f; unsigned short u; } v; v.f = h;
    return v.u;
}
__device__ __forceinline__ float h2f(unsigned short u) {
    union { unsigned short u; _Float16 f; } v; v.u = u;
    return (float)v.f;
}
__device__ __forceinline__ void gl_lds16(const unsigned short* g, unsigned short* l) {
    __builtin_amdgcn_global_load_lds(
        (const __attribute__((address_space(1))) unsigned int*)g,
        (__attribute__((address_space(3))) unsigned int*)l, 16, 0, 0);
}

// ---------- Mega kernel 1: all independent front-end jobs in one launch ----------
// job ranges (block id): [0,4096) prep | [.., +264) fold_ps | [.., +40) fold_ir
//                        | [.., +1024) bsplitT2 (psW1/irW1) | [.., +4096) bsplitTE (eW1/eW2)
#define MG_PREP 4096
#define MG_FPS  264
#define MG_FIR  40
#define MG_T2   1024
#define MG_TE   4096
#define MG_TOTAL (MG_PREP + MG_FPS + MG_FIR + MG_T2 + MG_TE)

__global__ __launch_bounds__(256) void k_mega1(
    const float* __restrict__ hidden, const float* __restrict__ feat,
    const float* __restrict__ lng, const float* __restrict__ lnb,
    unsigned short* __restrict__ Ahi, int* __restrict__ cz,
    const float* __restrict__ stageW, const float* __restrict__ stageb,
    const float* __restrict__ psW1, const float* __restrict__ psb1,
    float* __restrict__ Dps, float* __restrict__ fbps,
    const float* __restrict__ gfW, const float* __restrict__ gfb,
    const float* __restrict__ irW1, const float* __restrict__ irb1,
    float* __restrict__ Cir, float* __restrict__ fbir,
    unsigned short* __restrict__ Bhi,
    const float* __restrict__ eW1, const float* __restrict__ eW2,
    unsigned short* __restrict__ eW1T, unsigned short* __restrict__ eW2T)
{
    __shared__ float s_t[32][33];
    int bid = blockIdx.x;
    const int tid = threadIdx.x;

    if (bid < MG_PREP) {
        // ---- prep: LN + fp16 swizzled A (+ zero routing counters) ----
        if (bid == 0 && tid < 32) cz[tid] = 0;
        const int t = bid * 4 + (tid >> 6);
        const int lane = tid & 63;
        const float* row = hidden + (size_t)t * DMODEL;
        float4 v0 = ((const float4*)row)[lane * 2 + 0];
        float4 v1 = ((const float4*)row)[lane * 2 + 1];
        float s = v0.x + v0.y + v0.z + v0.w + v1.x + v1.y + v1.z + v1.w;
        #pragma unroll
        for (int m = 1; m < 64; m <<= 1) s += __shfl_xor(s, m);
        const float mu = s * (1.0f / DMODEL);
        float sq = 0.f;
        { float d;
          d = v0.x - mu; sq += d * d; d = v0.y - mu; sq += d * d;
          d = v0.z - mu; sq += d * d; d = v0.w - mu; sq += d * d;
          d = v1.x - mu; sq += d * d; d = v1.y - mu; sq += d * d;
          d = v1.z - mu; sq += d * d; d = v1.w - mu; sq += d * d; }
        #pragma unroll
        for (int m = 1; m < 64; m <<= 1) sq += __shfl_xor(sq, m);
        const float rstd = rsqrtf(sq * (1.0f / DMODEL) + 1e-5f);
        float4 g0 = ((const float4*)lng)[lane * 2 + 0];
        float4 g1 = ((const float4*)lng)[lane * 2 + 1];
        float4 b0 = ((const float4*)lnb)[lane * 2 + 0];
        float4 b1 = ((const float4*)lnb)[lane * 2 + 1];
        float h[8];
        h[0] = (v0.x - mu) * rstd * g0.x + b0.x;
        h[1] = (v0.y - mu) * rstd * g0.y + b0.y;
        h[2] = (v0.z - mu) * rstd * g0.z + b0.z;
        h[3] = (v0.w - mu) * rstd * g0.w + b0.w;
        h[4] = (v1.x - mu) * rstd * g1.x + b1.x;
        h[5] = (v1.y - mu) * rstd * g1.y + b1.y;
        h[6] = (v1.z - mu) * rstd * g1.z + b1.z;
        h[7] = (v1.w - mu) * rstd * g1.w + b1.w;
        const int q8 = ((t >> 1) & 3) * 8;
        ushort4 H0, H1;
        H0.x = f2h(h[0]); H0.y = f2h(h[1]); H0.z = f2h(h[2]); H0.w = f2h(h[3]);
        H1.x = f2h(h[4]); H1.y = f2h(h[5]); H1.z = f2h(h[6]); H1.w = f2h(h[7]);
        unsigned short* pa = Ahi + (size_t)t * RIN;
        const int dst = (lane >> 2) * 32 + (((lane & 3) * 8) ^ q8);
        *(ushort4*)&pa[dst] = H0;  *(ushort4*)&pa[dst + 4] = H1;
        const float fv = feat[(size_t)t * FFEAT + lane];
        const int fd = DMODEL + (lane & 32) + ((lane & 31) ^ q8);
        pa[fd] = f2h(fv);
        return;
    }
    bid -= MG_PREP;

    if (bid < MG_FPS) {
        // ---- fold_ps: 2 f-slots per 256-thread block ----
        const int g = bid / 33;
        const int f = (bid % 33) * 2 + (tid >> 7);
        const int c = tid & 127;
        const float* Wt = psW1 + (size_t)g * RIN * DRH + (size_t)DMODEL * DRH;
        float acc = 0.f;
        if (f < 64) {
            for (int j = 0; j < DFEMB; ++j) acc = fmaf(stageW[f * DFEMB + j], Wt[(size_t)j * DRH + c], acc);
            Dps[((size_t)g * 64 + f) * DRH + c] = acc;
        } else if (f == 64) {
            for (int j = 0; j < DFEMB; ++j) acc = fmaf(stageb[j], Wt[(size_t)j * DRH + c], acc);
            fbps[g * DRH + c] = acc + psb1[g * DRH + c];
        }
        return;
    }
    bid -= MG_FPS;

    if (bid < MG_FIR) {
        // ---- fold_ir: 2 f-slots per 256-thread block ----
        const int g = bid / 5;
        const int f = (bid % 5) * 2 + (tid >> 7);
        const int c = tid & 127;
        const float* Wt = irW1 + (size_t)g * RIN * DRH + (size_t)DMODEL * DRH;
        float acc = 0.f;
        if (f < 8) {
            for (int j = 0; j < DFEMB; ++j) acc = fmaf(gfW[(size_t)(g * 8 + f) * DFEMB + j], Wt[(size_t)j * DRH + c], acc);
            Cir[((size_t)g * 8 + f) * DRH + c] = acc;
        } else if (f == 8) {
            for (int j = 0; j < DFEMB; ++j) acc = fmaf(gfb[g * DFEMB + j], Wt[(size_t)j * DRH + c], acc);
            fbir[g * DRH + c] = acc + irb1[g * DRH + c];
        }
        return;
    }
    bid -= MG_FIR;

    if (bid < MG_T2) {
        // ---- router main-weight transpose: z=0 psW1, z=1 irW1 ----
        const int x = bid % 64, y = (bid / 64) % 8, z = bid / 512;
        const float* in = z ? irW1 : psW1;
        unsigned short* outHi = Bhi + (z ? (size_t)1024 * RIN : 0);
        const int tilesN = DRH >> 5;
        const int ko = (x / tilesN) << 5;
        const int no = (x % tilesN) << 5;
        const int r = tid >> 3, c0 = (tid & 7) * 4;
        {
            float4 v = *(const float4*)(in + (size_t)y * RIN * DRH + (size_t)(ko + r) * DRH + no + c0);
            s_t[r][c0] = v.x; s_t[r][c0 + 1] = v.y; s_t[r][c0 + 2] = v.z; s_t[r][c0 + 3] = v.w;
        }
        __syncthreads();
        float vv[4];
        #pragma unroll
        for (int j = 0; j < 4; ++j) vv[j] = s_t[c0 + j][r];
        const int col = no + r;
        const int q8 = ((col >> 1) & 3) * 8;
        ushort4 hi;
        hi.x = f2h(vv[0]); hi.y = f2h(vv[1]); hi.z = f2h(vv[2]); hi.w = f2h(vv[3]);
        *(ushort4*)(outHi + (size_t)y * DRH * RIN + (size_t)col * RIN + ko + (c0 ^ q8)) = hi;
        return;
    }
    bid -= MG_T2;

    {
        // ---- expert weight transpose: z=0 eW1 (512x256), z=1 eW2 (256x512) ----
        const int x = bid % 128, y = (bid / 128) % 16, z = bid / 2048;
        const int K = z ? DHID : DMODEL;
        const int N = z ? DMODEL : DHID;
        const float* in = z ? eW2 : eW1;
        unsigned short* outHi = z ? eW2T : eW1T;
        const long BS = (long)DMODEL * DHID;
        const int tilesN = N >> 5;
        const int ko = (x / tilesN) << 5;
        const int no = (x % tilesN) << 5;
        const int r = tid >> 3, c0 = (tid & 7) * 4;
        {
            float4 v = *(const float4*)(in + (size_t)y * BS + (size_t)(ko + r) * N + no + c0);
            s_t[r][c0] = v.x; s_t[r][c0 + 1] = v.y; s_t[r][c0 + 2] = v.z; s_t[r][c0 + 3] = v.w;
        }
        __syncthreads();
        float vv[4];
        #pragma unroll
        for (int j = 0; j < 4; ++j) vv[j] = s_t[c0 + j][r];
        const int col = no + r;
        const int q8 = ((col >> 1) & 3) * 8;
        ushort4 hi;
        hi.x = f2h(vv[0]); hi.y = f2h(vv[1]); hi.z = f2h(vv[2]); hi.w = f2h(vv[3]);
        *(ushort4*)(outHi + (size_t)y * BS + (size_t)col * K + ko + (c0 ^ q8)) = hi;
    }
}

// ---------- Mega kernel 2: fold-dependent jobs (Dps transpose + ir tail) ----------
// [0,64) bsplitT(Dps -> Bhi rows 512.., kOff=512) | [64,72) irtail
__global__ __launch_bounds__(256) void k_mega2(
    const float* __restrict__ Dps, const float* __restrict__ Cir,
    unsigned short* __restrict__ Bhi)
{
    __shared__ float s_t[32][33];
    int bid = blockIdx.x;
    const int tid = threadIdx.x;

    if (bid < 64) {
        // ---- transpose Dps[64][128] (per group) into Bhi cols, kOff=512 ----
        const int x = bid % 8, b = bid / 8;
        const int tilesN = DRH >> 5;                 // 4
        const int ko = (x / tilesN) << 5;            // 0 or 32
        const int no = (x % tilesN) << 5;
        const int r = tid >> 3, c0 = (tid & 7) * 4;
        {
            float4 v = *(const float4*)(Dps + (size_t)b * 64 * DRH + (size_t)(ko + r) * DRH + no + c0);
            s_t[r][c0] = v.x; s_t[r][c0 + 1] = v.y; s_t[r][c0 + 2] = v.z; s_t[r][c0 + 3] = v.w;
        }
        __syncthreads();
        float vv[4];
        #pragma unroll
        for (int j = 0; j < 4; ++j) vv[j] = s_t[c0 + j][r];
        const int col = no + r;
        const int q8 = ((col >> 1) & 3) * 8;
        ushort4 hi;
        hi.x = f2h(vv[0]); hi.y = f2h(vv[1]); hi.z = f2h(vv[2]); hi.w = f2h(vv[3]);
        *(ushort4*)(Bhi + (size_t)b * DRH * RIN + (size_t)col * RIN + 512 + ko + (c0 ^ q8)) = hi;
        return;
    }
    bid -= 64;

    {
        // ---- ir tail rows of B: f-range split across half-blocks ----
        const int g = bid;
        const int c = tid & 127;
        const int h = tid >> 7;
        const int col = 1024 + g * DRH + c;
        const int q8 = ((col >> 1) & 3) * 8;
        unsigned short* ph = Bhi + (size_t)col * RIN + DMODEL;
        for (int f = h * 32; f < h * 32 + 32; ++f) {
            float v = ((f >> 3) == g) ? Cir[((size_t)g * 8 + (f & 7)) * DRH + c] : 0.f;
            const int d = (f & 32) + ((f & 31) ^ q8);
            ph[d] = f2h(v);
        }
    }
}

// ---------- Kernel 2: router GEMM, 8-wave 128x128, depth-3 counted-vmcnt (R13 verified) ----------
__global__ __launch_bounds__(512) void k_rgemm(
    const unsigned short* __restrict__ Ahi, const unsigned short* __restrict__ Bhi,
    const float* __restrict__ fbps, const float* __restrict__ psW2, const float* __restrict__ psb2,
    const float* __restrict__ fbir, const float* __restrict__ irW2, const float* __restrict__ irb2,
    float* __restrict__ glog, float* __restrict__ ilog)
{
    __shared__ unsigned short sAh[3][128 * 32];
    __shared__ unsigned short sBh[3][128 * 32];
    __shared__ float s_red[2][4][64][2];

    const int tid = threadIdx.x, lane = tid & 63, w = tid >> 6;
    const int t0 = blockIdx.x * 128, bn = blockIdx.y;
    const int wm = w >> 2, wn = w & 3;
    const int arow = lane & 15, koff = (lane >> 4) * 8;
    const int q8r = ((arow >> 1) & 3) * 8;

    int aoff[4], boff[2];
    #pragma unroll
    for (int m = 0; m < 4; ++m) aoff[m] = (wm * 64 + m * 16 + arow) * 32 + (koff ^ q8r);
    #pragma unroll
    for (int n = 0; n < 2; ++n) boff[n] = (wn * 32 + n * 16 + arow) * 32 + (koff ^ q8r);

    const int srow = w * 16 + (lane >> 2);
    const int sgr = (lane & 3) * 8;
    const unsigned short* gAh = Ahi + (size_t)(t0 + srow) * RIN + sgr;
    const unsigned short* gBh = Bhi + (size_t)(bn * 128 + srow) * RIN + sgr;

    f32x4 acc[4][2];
    #pragma unroll
    for (int m = 0; m < 4; ++m)
        #pragma unroll
        for (int n = 0; n < 2; ++n) { acc[m][n].x = 0.f; acc[m][n].y = 0.f; acc[m][n].z = 0.f; acc[m][n].w = 0.f; }

    auto STAGE = [&](int b, int kt) {
        const int kk = kt * 32;
        gl_lds16(gAh + kk, &sAh[b][w * 512]);
        gl_lds16(gBh + kk, &sBh[b][w * 512]);
    };

    STAGE(0, 0);
    STAGE(1, 1);
    for (int kt = 0; kt < 18; ++kt) {
        const int slot = kt % 3;
        if (kt + 2 < 18) { STAGE((kt + 2) % 3, kt + 2); WAIT_VM(4); }
        else if (kt + 1 < 18) { WAIT_VM(2); }
        else { WAIT_VM(0); }
        __builtin_amdgcn_s_barrier();
        __builtin_amdgcn_sched_barrier(0);
        f16x8 ah[4];
        #pragma unroll
        for (int m = 0; m < 4; ++m) ah[m] = *(const f16x8*)&sAh[slot][aoff[m]];
        #pragma unroll
        for (int n = 0; n < 2; ++n) {
            f16x8 b = *(const f16x8*)&sBh[slot][boff[n]];
            #pragma unroll
            for (int m = 0; m < 4; ++m) acc[m][n] = MFMA16F(ah[m], b, acc[m][n]);
        }
        __builtin_amdgcn_s_barrier();
    }

    // fused second layer (one group per block)
    const bool isPS = (bn < 8);
    const int g = bn & 7;
    const int q = lane >> 4;
    if (isPS) {
        float r0[4][4] = {};
        #pragma unroll
        for (int n = 0; n < 2; ++n) {
            const int cg = wn * 32 + n * 16 + arow;
            const float b1 = fbps[g * DRH + cg];
            const float w2 = psW2[g * DRH + cg];
            #pragma unroll
            for (int m = 0; m < 4; ++m)
                #pragma unroll
                for (int j = 0; j < 4; ++j)
                    r0[m][j] += gelu_f(acc[m][n][j] + b1) * w2;
        }
        #pragma unroll
        for (int mk = 1; mk < 16; mk <<= 1)
            #pragma unroll
            for (int m = 0; m < 4; ++m)
                #pragma unroll
                for (int j = 0; j < 4; ++j) r0[m][j] += __shfl_xor(r0[m][j], mk);
        if (arow == 0) {
            #pragma unroll
            for (int m = 0; m < 4; ++m)
                #pragma unroll
                for (int j = 0; j < 4; ++j) {
                    s_red[wm][wn][m * 16 + q * 4 + j][0] = r0[m][j];
                }
        }
    } else {
        float r0[4][4] = {}, r1[4][4] = {};
        #pragma unroll
        for (int n = 0; n < 2; ++n) {
            const int cg = wn * 32 + n * 16 + arow;
            const float b1 = fbir[g * DRH + cg];
            const float w20 = irW2[(size_t)(g * DRH + cg) * NES + 0];
            const float w21 = irW2[(size_t)(g * DRH + cg) * NES + 1];
            #pragma unroll
            for (int m = 0; m < 4; ++m)
                #pragma unroll
                for (int j = 0; j < 4; ++j) {
                    const float v = gelu_f(acc[m][n][j] + b1);
                    r0[m][j] = fmaf(v, w20, r0[m][j]);
                    r1[m][j] = fmaf(v, w21, r1[m][j]);
                }
        }
        #pragma unroll
        for (int mk = 1; mk < 16; mk <<= 1)
            #pragma unroll
            for (int m = 0; m < 4; ++m)
                #pragma unroll
                for (int j = 0; j < 4; ++j) {
                    r0[m][j] += __shfl_xor(r0[m][j], mk);
                    r1[m][j] += __shfl_xor(r1[m][j], mk);
                }
        if (arow == 0) {
            #pragma unroll
            for (int m = 0; m < 4; ++m)
                #pragma unroll
                for (int j = 0; j < 4; ++j) {
                    s_red[wm][wn][m * 16 + q * 4 + j][0] = r0[m][j];
                    s_red[wm][wn][m * 16 + q * 4 + j][1] = r1[m][j];
                }
        }
    }
    __syncthreads();
    if (tid < 128) {
        const int row = tid;
        const int wmm = row >> 6, rl = row & 63;
        if (isPS) {
            float v0 = s_red[wmm][0][rl][0] + s_red[wmm][1][rl][0]
                     + s_red[wmm][2][rl][0] + s_red[wmm][3][rl][0];
            glog[(size_t)(t0 + row) * NG + g] = v0 + psb2[g];
        } else {
            float v0 = s_red[wmm][0][rl][0] + s_red[wmm][1][rl][0]
                     + s_red[wmm][2][rl][0] + s_red[wmm][3][rl][0];
            float v1 = s_red[wmm][0][rl][1] + s_red[wmm][1][rl][1]
                     + s_red[wmm][2][rl][1] + s_red[wmm][3][rl][1];
            const size_t bidx = ((size_t)(t0 + row) * NG + g) * NES;
            ilog[bidx + 0] = v0 + irb2[g * NES + 0];
            ilog[bidx + 1] = v1 + irb2[g * NES + 1];
        }
    }
}

// ---------- Kernel 2b: finalize, block-aggregated atomics ----------
#define MARGIN 4e-3f
__global__ __launch_bounds__(256) void hg_finalize2(
    const float* __restrict__ glog_buf, const float* __restrict__ ilog_buf,
    int* __restrict__ counts, int* __restrict__ nfix, int* __restrict__ fix_list,
    int* __restrict__ list_tok, float* __restrict__ list_w, int* __restrict__ list_slot)
{
    __shared__ int s_cnt[NE];
    __shared__ int s_base[NE];
    __shared__ int s_fcnt, s_fbase;

    const int tid = threadIdx.x;
    const int t = blockIdx.x * 256 + tid;
    if (tid < NE) s_cnt[tid] = 0;
    if (tid == 0) s_fcnt = 0;
    __syncthreads();

    float gl[NG];
    *(float4*)&gl[0] = ((const float4*)(glog_buf + (size_t)t * NG))[0];
    *(float4*)&gl[4] = ((const float4*)(glog_buf + (size_t)t * NG))[1];
    int i1 = 0; float m1 = gl[0];
    #pragma unroll
    for (int g = 1; g < NG; ++g) if (gl[g] > m1) { m1 = gl[g]; i1 = g; }
    int i2 = -1; float m2 = -3.4e38f;
    #pragma unroll
    for (int g = 0; g < NG; ++g) if (g != i1 && gl[g] > m2) { m2 = gl[g]; i2 = g; }
    float m3 = -3.4e38f;
    #pragma unroll
    for (int g = 0; g < NG; ++g) if (g != i1 && g != i2 && gl[g] > m3) m3 = gl[g];

    const float ila0 = ilog_buf[((size_t)t * NG + i1) * NES + 0];
    const float ila1 = ilog_buf[((size_t)t * NG + i1) * NES + 1];
    const float ilb0 = ilog_buf[((size_t)t * NG + i2) * NES + 0];
    const float ilb1 = ilog_buf[((size_t)t * NG + i2) * NES + 1];

    const bool flag = ((m2 - m3) < MARGIN) || (fabsf(ila1 - ila0) < MARGIN)
                   || (fabsf(ilb1 - ilb0) < MARGIN);

    const float ex = expf(m2 - m1);
    const float inv = 1.0f / (1.0f + ex);
    const int   gsel[2] = {i1, i2};
    const float wsel[2] = {inv, ex * inv};
    const int   ksel[2] = {(ila1 > ila0) ? 1 : 0, (ilb1 > ilb0) ? 1 : 0};

    int eid[2] = {0, 0}, lo[2] = {0, 0}, fo = 0;
    if (!flag) {
        #pragma unroll
        for (int s = 0; s < 2; ++s) {
            eid[s] = gsel[s] * NES + ksel[s];
            lo[s] = atomicAdd(&s_cnt[eid[s]], 1);
        }
    } else {
        fo = atomicAdd(&s_fcnt, 1);
    }
    __syncthreads();
    if (tid < NE) s_base[tid] = atomicAdd(&counts[tid], s_cnt[tid]);
    if (tid == 16) s_fbase = atomicAdd(nfix, s_fcnt);
    __syncthreads();

    if (!flag) {
        #pragma unroll
        for (int s = 0; s < 2; ++s) {
            const int pos = s_base[eid[s]] + lo[s];
            list_tok[(size_t)eid[s] * T_TOKENS + pos] = t;
            list_w[(size_t)eid[s] * T_TOKENS + pos] = wsel[s];
            list_slot[(size_t)eid[s] * T_TOKENS + pos] = s;
        }
    } else {
        fix_list[s_fbase + fo] = t;
    }
}

// ---------- Kernel 2c: exact fp32 fixup, 4-wave parallel, unrolled ----------
__global__ __launch_bounds__(256) void hg_fixup(
    const float* __restrict__ hidden, const float* __restrict__ feat,
    const float* __restrict__ lng, const float* __restrict__ lnb,
    const float* __restrict__ stageW, const float* __restrict__ stageb,
    const float* __restrict__ gfW, const float* __restrict__ gfb,
    const float* __restrict__ psW1, const float* __restrict__ psb1,
    const float* __restrict__ psW2, const float* __restrict__ psb2,
    const float* __restrict__ irW1, const float* __restrict__ irb1,
    const float* __restrict__ irW2, const float* __restrict__ irb2,
    const int* __restrict__ nfix, const int* __restrict__ fix_list,
    int* __restrict__ counts, int* __restrict__ list_tok, float* __restrict__ list_w,
    int* __restrict__ list_slot)
{
    __shared__ float s_rin[RIN];
    __shared__ float s_tail[2][DFEMB];
    __shared__ float s_gl[NG];
    __shared__ float s_part[4][2];
    __shared__ int s_sel[2];
    __shared__ float s_wsel[2];

    const int tid = threadIdx.x, lane = tid & 63, w = tid >> 6;
    const int nf = nfix[0];
    for (int idx = blockIdx.x; idx < nf; idx += gridDim.x) {
        const int t = fix_list[idx];
        if (w == 0) {
            const float* row = hidden + (size_t)t * DMODEL;
            float4 v0 = ((const float4*)row)[lane * 2 + 0];
            float4 v1 = ((const float4*)row)[lane * 2 + 1];
            float s = v0.x + v0.y + v0.z + v0.w + v1.x + v1.y + v1.z + v1.w;
            #pragma unroll
            for (int m = 1; m < 64; m <<= 1) s += __shfl_xor(s, m);
            const float mu = s * (1.0f / DMODEL);
            float sq = 0.f;
            { float d;
              d = v0.x - mu; sq += d * d; d = v0.y - mu; sq += d * d;
              d = v0.z - mu; sq += d * d; d = v0.w - mu; sq += d * d;
              d = v1.x - mu; sq += d * d; d = v1.y - mu; sq += d * d;
              d = v1.z - mu; sq += d * d; d = v1.w - mu; sq += d * d; }
            #pragma unroll
            for (int m = 1; m < 64; m <<= 1) sq += __shfl_xor(sq, m);
            const float rstd = rsqrtf(sq * (1.0f / DMODEL) + 1e-5f);
            float4 g0 = ((const float4*)lng)[lane * 2 + 0];
            float4 g1 = ((const float4*)lng)[lane * 2 + 1];
            float4 b0 = ((const float4*)lnb)[lane * 2 + 0];
            float4 b1 = ((const float4*)lnb)[lane * 2 + 1];
            s_rin[lane * 8 + 0] = (v0.x - mu) * rstd * g0.x + b0.x;
            s_rin[lane * 8 + 1] = (v0.y - mu) * rstd * g0.y + b0.y;
            s_rin[lane * 8 + 2] = (v0.z - mu) * rstd * g0.z + b0.z;
            s_rin[lane * 8 + 3] = (v0.w - mu) * rstd * g0.w + b0.w;
            s_rin[lane * 8 + 4] = (v1.x - mu) * rstd * g1.x + b1.x;
            s_rin[lane * 8 + 5] = (v1.y - mu) * rstd * g1.y + b1.y;
            s_rin[lane * 8 + 6] = (v1.z - mu) * rstd * g1.z + b1.z;
            s_rin[lane * 8 + 7] = (v1.w - mu) * rstd * g1.w + b1.w;
        } else if (w == 1) {
            float se = stageb[lane];
            #pragma unroll 8
            for (int f = 0; f < FFEAT; ++f)
                se = fmaf(feat[(size_t)t * FFEAT + f], stageW[f * DFEMB + lane], se);
            s_rin[DMODEL + lane] = se;
        }
        __syncthreads();

        #pragma unroll
        for (int gi = 0; gi < 2; ++gi) {
            const int g = w * 2 + gi;
            float a0 = psb1[g * DRH + lane];
            float a1 = psb1[g * DRH + 64 + lane];
            const float* W = psW1 + (size_t)g * RIN * DRH;
            #pragma unroll 8
            for (int k = 0; k < RIN; ++k) {
                const float r = s_rin[k];
                a0 = fmaf(r, W[(size_t)k * DRH + lane], a0);
                a1 = fmaf(r, W[(size_t)k * DRH + 64 + lane], a1);
            }
            float p = gelu_f(a0) * psW2[g * DRH + lane] + gelu_f(a1) * psW2[g * DRH + 64 + lane];
            #pragma unroll
            for (int m = 1; m < 64; m <<= 1) p += __shfl_xor(p, m);
            if (lane == 0) s_gl[g] = p + psb2[g];
        }
        __syncthreads();

        if (tid == 0) {
            int i1 = 0; float m1 = s_gl[0];
            #pragma unroll
            for (int g = 1; g < NG; ++g) if (s_gl[g] > m1) { m1 = s_gl[g]; i1 = g; }
            int i2 = -1; float m2 = -3.4e38f;
            #pragma unroll
            for (int g = 0; g < NG; ++g) if (g != i1 && s_gl[g] > m2) { m2 = s_gl[g]; i2 = g; }
            const float ex = expf(m2 - m1);
            const float inv = 1.0f / (1.0f + ex);
            s_sel[0] = i1; s_sel[1] = i2;
            s_wsel[0] = inv; s_wsel[1] = ex * inv;
        }
        __syncthreads();

        const int pr = w >> 1;
        const int gsel = s_sel[pr];
        if ((w & 1) == 0) {
            float ge = gfb[gsel * DFEMB + lane];
            #pragma unroll
            for (int f = 0; f < 8; ++f)
                ge = fmaf(feat[(size_t)t * FFEAT + gsel * 8 + f],
                          gfW[(size_t)(gsel * 8 + f) * DFEMB + lane], ge);
            s_tail[pr][lane] = ge;
        }
        __syncthreads();

        {
            const int col = (w & 1) * 64 + lane;
            float a = irb1[gsel * DRH + col];
            const float* W = irW1 + (size_t)gsel * RIN * DRH + col;
            #pragma unroll 8
            for (int k = 0; k < DMODEL; ++k)
                a = fmaf(s_rin[k], W[(size_t)k * DRH], a);
            #pragma unroll 8
            for (int k = 0; k < DFEMB; ++k)
                a = fmaf(s_tail[pr][k], W[(size_t)(DMODEL + k) * DRH], a);
            const float v = gelu_f(a);
            float e0 = v * irW2[(size_t)(gsel * DRH + col) * NES + 0];
            float e1 = v * irW2[(size_t)(gsel * DRH + col) * NES + 1];
            #pragma unroll
            for (int m = 1; m < 64; m <<= 1) {
                e0 += __shfl_xor(e0, m);
                e1 += __shfl_xor(e1, m);
            }
            if (lane == 0) { s_part[w][0] = e0; s_part[w][1] = e1; }
        }
        __syncthreads();

        if (tid == 0) {
            #pragma unroll
            for (int p2 = 0; p2 < 2; ++p2) {
                const float e0 = s_part[p2 * 2][0] + s_part[p2 * 2 + 1][0];
                const float e1 = s_part[p2 * 2][1] + s_part[p2 * 2 + 1][1];
                const int eid = s_sel[p2] * NES + ((e1 > e0) ? 1 : 0);
                const int pos = atomicAdd(&counts[eid], 1);
                list_tok[(size_t)eid * T_TOKENS + pos] = t;
                list_w[(size_t)eid * T_TOKENS + pos] = s_wsel[p2];
                list_slot[(size_t)eid * T_TOKENS + pos] = p2;
            }
        }
        __syncthreads();
    }
}

// ---------- Kernel 3a: expert GEMM1 -> ehbuf (depth-3 pipeline) ----------
__global__ __launch_bounds__(256) void k_e1(
    const unsigned short* __restrict__ Ahi,
    const unsigned short* __restrict__ eW1T, const float* __restrict__ eb1,
    const int* __restrict__ counts, const int* __restrict__ list_tok,
    const int* __restrict__ list_slot, unsigned short* __restrict__ ehbuf)
{
    __shared__ unsigned short sA[3][64 * 32];
    __shared__ unsigned short sB[3][256 * 32];
    __shared__ int s_tok[64];
    __shared__ int s_pair[64];

    const int e = blockIdx.y;
    const int cnt = counts[e];
    const int base = blockIdx.x * 64;
    if (base >= cnt) return;
    const int nrow = min(64, cnt - base);
    const int tid = threadIdx.x, lane = tid & 63, w = tid >> 6;

    if (tid < 64) {
        const int src = base + ((tid < nrow) ? tid : (nrow - 1));
        s_tok[tid] = list_tok[(size_t)e * T_TOKENS + src];
        s_pair[tid] = s_tok[tid] * 2 + list_slot[(size_t)e * T_TOKENS + src];
    }
    __syncthreads();

    const int srow = w * 16 + (lane >> 2);
    const int stok = s_tok[srow];
    const int qcor = ((srow >> 1) & 3) ^ ((stok >> 1) & 3);
    const unsigned short* gA = Ahi + (size_t)stok * RIN + 8 * ((lane & 3) ^ qcor);
    const int sgr = (lane & 3) * 8;
    const unsigned short* gB[4];
    #pragma unroll
    for (int i = 0; i < 4; ++i)
        gB[i] = eW1T + (size_t)e * DHID * DMODEL + (size_t)(w * 64 + i * 16 + (lane >> 2)) * DMODEL + sgr;

    const int arow = lane & 15, koff = (lane >> 4) * 8;
    const int q8r = ((arow >> 1) & 3) * 8;
    int aoff[4], boff[4];
    #pragma unroll
    for (int m = 0; m < 4; ++m) aoff[m] = (m * 16 + arow) * 32 + (koff ^ q8r);
    #pragma unroll
    for (int n = 0; n < 4; ++n) boff[n] = (w * 64 + n * 16 + arow) * 32 + (koff ^ q8r);

    f32x4 acc[4][4];
    #pragma unroll
    for (int m = 0; m < 4; ++m)
        #pragma unroll
        for (int n = 0; n < 4; ++n) { acc[m][n].x = 0.f; acc[m][n].y = 0.f; acc[m][n].z = 0.f; acc[m][n].w = 0.f; }

    auto STAGE = [&](int b, int kt) {
        const int kk = kt * 32;
        gl_lds16(gA + kk, &sA[b][w * 512]);
        #pragma unroll
        for (int i = 0; i < 4; ++i) gl_lds16(gB[i] + kk, &sB[b][w * 2048 + i * 512]);
    };

    STAGE(0, 0);
    STAGE(1, 1);
    for (int kt = 0; kt < 16; ++kt) {
        const int slot = kt % 3;
        if (kt + 2 < 16) { STAGE((kt + 2) % 3, kt + 2); WAIT_VM(10); }
        else if (kt + 1 < 16) { WAIT_VM(5); }
        else { WAIT_VM(0); }
        __builtin_amdgcn_s_barrier();
        __builtin_amdgcn_sched_barrier(0);
        f16x8 a[4];
        #pragma unroll
        for (int m = 0; m < 4; ++m) a[m] = *(const f16x8*)&sA[slot][aoff[m]];
        #pragma unroll
        for (int n = 0; n < 4; ++n) {
            f16x8 b = *(const f16x8*)&sB[slot][boff[n]];
            #pragma unroll
            for (int m = 0; m < 4; ++m) acc[m][n] = MFMA16F(a[m], b, acc[m][n]);
        }
        __builtin_amdgcn_s_barrier();
    }

    const int q = lane >> 4;
    #pragma unroll
    for (int m = 0; m < 4; ++m)
        #pragma unroll
        for (int n = 0; n < 4; ++n) {
            const int col = w * 64 + n * 16 + arow;
            const float bv = eb1[e * DHID + col];
            #pragma unroll
            for (int j = 0; j < 4; ++j) {
                const int rr = m * 16 + q * 4 + j;
                if (rr < nrow) {   // padded rows alias real ehbuf rows with a different swizzle key -> must skip
                    const size_t d = (size_t)s_pair[rr] * DHID
                                   + (col & 0xE0) + ((col & 31) ^ (((rr >> 1) & 3) * 8));
                    ehbuf[d] = f2h(gelu_f(acc[m][n][j] + bv));
                }
            }
        }
}

// ---------- Kernel 3b: expert GEMM2 -> contrib (depth-3 pipeline) ----------
__global__ __launch_bounds__(256) void k_e2(
    const unsigned short* __restrict__ ehbuf,
    const unsigned short* __restrict__ eW2T, const float* __restrict__ eb2,
    const float* __restrict__ alpha_p,
    const int* __restrict__ counts, const int* __restrict__ list_tok,
    const float* __restrict__ list_w, const int* __restrict__ list_slot,
    unsigned short* __restrict__ contrib)
{
    __shared__ unsigned short sA[3][64 * 32];
    __shared__ unsigned short sB[3][256 * 32];
    __shared__ int s_pair[64];
    __shared__ float s_w[64];

    const int e = blockIdx.y;
    const int cnt = counts[e];
    const int base = blockIdx.x * 64;
    if (base >= cnt) return;
    const int ch = blockIdx.z;
    const int nrow = min(64, cnt - base);
    const int tid = threadIdx.x, lane = tid & 63, w = tid >> 6;

    if (tid < 64) {
        const int src = base + ((tid < nrow) ? tid : (nrow - 1));
        const int tok = list_tok[(size_t)e * T_TOKENS + src];
        s_pair[tid] = tok * 2 + list_slot[(size_t)e * T_TOKENS + src];
        s_w[tid] = (tid < nrow) ? list_w[(size_t)e * T_TOKENS + base + tid] : 0.f;
    }
    __syncthreads();

    const int srow = w * 16 + (lane >> 2);
    const unsigned short* gA = ehbuf + (size_t)s_pair[srow] * DHID + (lane & 3) * 8;
    const int sgr = (lane & 3) * 8;
    const unsigned short* gB[4];
    #pragma unroll
    for (int i = 0; i < 4; ++i)
        gB[i] = eW2T + (size_t)e * DMODEL * DHID
              + (size_t)(ch * 256 + w * 64 + i * 16 + (lane >> 2)) * DHID + sgr;

    const int arow = lane & 15, koff = (lane >> 4) * 8;
    const int q8r = ((arow >> 1) & 3) * 8;
    int aoff[4], boff[4];
    #pragma unroll
    for (int m = 0; m < 4; ++m) aoff[m] = (m * 16 + arow) * 32 + (koff ^ q8r);
    #pragma unroll
    for (int n = 0; n < 4; ++n) boff[n] = (w * 64 + n * 16 + arow) * 32 + (koff ^ q8r);

    f32x4 acc[4][4];
    #pragma unroll
    for (int m = 0; m < 4; ++m)
        #pragma unroll
        for (int n = 0; n < 4; ++n) { acc[m][n].x = 0.f; acc[m][n].y = 0.f; acc[m][n].z = 0.f; acc[m][n].w = 0.f; }

    auto STAGE = [&](int b, int kt) {
        const int kk = kt * 32;
        gl_lds16(gA + kk, &sA[b][w * 512]);
        #pragma unroll
        for (int i = 0; i < 4; ++i) gl_lds16(gB[i] + kk, &sB[b][w * 2048 + i * 512]);
    };

    STAGE(0, 0);
    STAGE(1, 1);
    for (int kt = 0; kt < 8; ++kt) {
        const int slot = kt % 3;
        if (kt + 2 < 8) { STAGE((kt + 2) % 3, kt + 2); WAIT_VM(10); }
        else if (kt + 1 < 8) { WAIT_VM(5); }
        else { WAIT_VM(0); }
        __builtin_amdgcn_s_barrier();
        __builtin_amdgcn_sched_barrier(0);
        f16x8 a[4];
        #pragma unroll
        for (int m = 0; m < 4; ++m) a[m] = *(const f16x8*)&sA[slot][aoff[m]];
        #pragma unroll
        for (int n = 0; n < 4; ++n) {
            f16x8 b = *(const f16x8*)&sB[slot][boff[n]];
            #pragma unroll
            for (int m = 0; m < 4; ++m) acc[m][n] = MFMA16F(a[m], b, acc[m][n]);
        }
        __builtin_amdgcn_s_barrier();
    }

    const float alpha = alpha_p[0];
    const int q = lane >> 4;
    #pragma unroll
    for (int m = 0; m < 4; ++m)
        #pragma unroll
        for (int n = 0; n < 4; ++n) {
            const int col = ch * 256 + w * 64 + n * 16 + arow;
            const float b2v = eb2[e * DMODEL + col];
            #pragma unroll
            for (int j = 0; j < 4; ++j) {
                const int r = m * 16 + q * 4 + j;
                if (r < nrow)
                    contrib[(size_t)s_pair[r] * DMODEL + col] =
                        f2h(s_w[r] * alpha * (acc[m][n][j] + b2v));
            }
        }
}

// ---------- Kernel 4: combine out = hidden + c0 + c1 ----------
__global__ __launch_bounds__(256) void k_combine(
    const float* __restrict__ hidden, const unsigned short* __restrict__ contrib,
    float* __restrict__ out)
{
    const size_t gid = (size_t)blockIdx.x * 256 + threadIdx.x;
    const int t = (int)(gid >> 6);
    const int c = (int)(gid & 63) * 8;
    const float* hp = hidden + (size_t)t * DMODEL + c;
    float4 h0 = ((const float4*)hp)[0];
    float4 h1 = ((const float4*)hp)[1];
    const unsigned short* c0p = contrib + ((size_t)t * 2 + 0) * DMODEL + c;
    const unsigned short* c1p = contrib + ((size_t)t * 2 + 1) * DMODEL + c;
    ushort4 a0 = ((const ushort4*)c0p)[0], a1 = ((const ushort4*)c0p)[1];
    ushort4 b0 = ((const ushort4*)c1p)[0], b1 = ((const ushort4*)c1p)[1];
    float4 o0, o1;
    o0.x = h0.x + h2f(a0.x) + h2f(b0.x);
    o0.y = h0.y + h2f(a0.y) + h2f(b0.y);
    o0.z = h0.z + h2f(a0.z) + h2f(b0.z);
    o0.w = h0.w + h2f(a0.w) + h2f(b0.w);
    o1.x = h1.x + h2f(a1.x) + h2f(b1.x);
    o1.y = h1.y + h2f(a1.y) + h2f(b1.y);
    o1.z = h1.z + h2f(a1.z) + h2f(b1.z);
    o1.w = h1.w + h2f(a1.w) + h2f(b1.w);
    float* op = out + (size_t)t * DMODEL + c;
    ((float4*)op)[0] = o0;
    ((float4*)op)[1] = o1;
}

// ---------- launch ----------
extern "C" void kernel_launch(void* const* d_in, const int* in_sizes, int n_in,
                              void* d_out, int out_size, void* d_ws, size_t ws_size,
                              hipStream_t stream) {
    const float* hidden = (const float*)d_in[0];
    const float* feat   = (const float*)d_in[1];
    const float* ln_g   = (const float*)d_in[2];
    const float* ln_b   = (const float*)d_in[3];
    const float* stageW = (const float*)d_in[4];
    const float* stageb = (const float*)d_in[5];
    const float* gfW    = (const float*)d_in[6];
    const float* gfb    = (const float*)d_in[7];
    const float* psW1   = (const float*)d_in[8];
    const float* psb1   = (const float*)d_in[9];
    const float* psW2   = (const float*)d_in[10];
    const float* psb2   = (const float*)d_in[11];
    const float* irW1   = (const float*)d_in[12];
    const float* irb1   = (const float*)d_in[13];
    const float* irW2   = (const float*)d_in[14];
    const float* irb2   = (const float*)d_in[15];
    const float* eW1    = (const float*)d_in[16];
    const float* eb1    = (const float*)d_in[17];
    const float* eW2    = (const float*)d_in[18];
    const float* eb2    = (const float*)d_in[19];
    const float* alpha  = (const float*)d_in[20];

    float* out = (float*)d_out;

    char* p = (char*)d_ws;
    unsigned short* Ahi = (unsigned short*)p; p += (size_t)T_TOKENS * RIN * 2;
    unsigned short* Bhi = (unsigned short*)p; p += (size_t)2048 * RIN * 2;
    unsigned short* eW1T = (unsigned short*)p; p += (size_t)NE * DHID * DMODEL * 2;
    unsigned short* eW2T = (unsigned short*)p; p += (size_t)NE * DMODEL * DHID * 2;
    unsigned short* contrib = (unsigned short*)p; p += (size_t)T_TOKENS * 2 * DMODEL * 2;
    unsigned short* ehbuf = (unsigned short*)p; p += (size_t)T_TOKENS * 2 * DHID * 2;
    float* Dps = (float*)p;   p += (size_t)NG * 64 * DRH * 4;
    float* Cir = (float*)p;   p += (size_t)NG * 8 * DRH * 4;
    float* fbps = (float*)p;  p += (size_t)NG * DRH * 4;
    float* fbir = (float*)p;  p += (size_t)NG * DRH * 4;
    float* glog_buf = (float*)p; p += (size_t)T_TOKENS * NG * 4;
    float* ilog_buf = (float*)p; p += (size_t)T_TOKENS * NG * NES * 4;
    int* counts = (int*)p;    p += 128;
    int* nfix = counts + 16;
    int* fix_list = (int*)p;  p += (size_t)T_TOKENS * 4;
    int* list_tok = (int*)p;  p += (size_t)NE * T_TOKENS * 4;
    float* list_w = (float*)p; p += (size_t)NE * T_TOKENS * 4;
    int* list_slot = (int*)p; p += (size_t)NE * T_TOKENS * 4;

    k_mega1<<<MG_TOTAL, 256, 0, stream>>>(
        hidden, feat, ln_g, ln_b, Ahi, counts,
        stageW, stageb, psW1, psb1, Dps, fbps,
        gfW, gfb, irW1, irb1, Cir, fbir,
        Bhi, eW1, eW2, eW1T, eW2T);

    k_mega2<<<72, 256, 0, stream>>>(Dps, Cir, Bhi);

    k_rgemm<<<dim3(T_TOKENS / 128, 16), 512, 0, stream>>>(
        Ahi, Bhi, fbps, psW2, psb2, fbir, irW2, irb2, glog_buf, ilog_buf);

    hg_finalize2<<<T_TOKENS / 256, 256, 0, stream>>>(
        glog_buf, ilog_buf, counts, nfix, fix_list, list_tok, list_w, list_slot);

    hg_fixup<<<1024, 256, 0, stream>>>(
        hidden, feat, ln_g, ln_b, stageW, stageb, gfW, gfb,
        psW1, psb1, psW2, psb2, irW1, irb1, irW2, irb2,
        nfix, fix_list, counts, list_tok, list_w, list_slot);

    k_e1<<<dim3(T_TOKENS / 64, NE), 256, 0, stream>>>(
        Ahi, eW1T, eb1, counts, list_tok, list_slot, ehbuf);

    k_e2<<<dim3(T_TOKENS / 64, NE, 2), 256, 0, stream>>>(
        ehbuf, eW2T, eb2, alpha, counts, list_tok, list_w, list_slot, contrib);

    k_combine<<<(T_TOKENS * DMODEL / 8) / 256, 256, 0, stream>>>(hidden, contrib, out);
}

// Round 26
// 313.158 us; speedup vs baseline: 1.1148x; 1.0329x over previous
//
#include <hip/hip_runtime.h>
#include <hip/hip_bf16.h>

#define T_TOKENS 16384
#define DMODEL 512
#define FFEAT 64
#define DFEMB 64
#define RIN 576
#define DRH 128
#define NG 8
#define NES 2
#define NE 16
#define DHID 256

typedef float f32x4 __attribute__((ext_vector_type(4)));
typedef _Float16 f16x8 __attribute__((ext_vector_type(8)));
#define MFMA16F(a, b, c) __builtin_amdgcn_mfma_f32_16x16x32_f16((a), (b), (c), 0, 0, 0)
#define WAIT_VM(N) asm volatile("s_waitcnt vmcnt(" #N ")" ::: "memory")

__device__ __forceinline__ float gelu_f(float x) {
    return 0.5f * x * (1.0f + erff(x * 0.7071067811865476f));
}
__device__ __forceinline__ unsigned short f2h(float x) {
    _Float16 h = (_Float16)x;
    union { _Float16 f; unsigned short u; } v; v.f = h;
    return v.u;
}
__device__ __forceinline__ float h2f(unsigned short u) {
    union { unsigned short u; _Float16 f; } v; v.u = u;
    return (float)v.f;
}
__device__ __forceinline__ void gl_lds16(const unsigned short* g, unsigned short* l) {
    __builtin_amdgcn_global_load_lds(
        (const __attribute__((address_space(1))) unsigned int*)g,
        (__attribute__((address_space(3))) unsigned int*)l, 16, 0, 0);
}

// ---------- Mega kernel 1: all independent front-end jobs in one launch ----------
#define MG_PREP 4096
#define MG_FPS  264
#define MG_FIR  40
#define MG_T2   1024
#define MG_TE   4096
#define MG_TOTAL (MG_PREP + MG_FPS + MG_FIR + MG_T2 + MG_TE)

__global__ __launch_bounds__(256) void k_mega1(
    const float* __restrict__ hidden, const float* __restrict__ feat,
    const float* __restrict__ lng, const float* __restrict__ lnb,
    unsigned short* __restrict__ Ahi, int* __restrict__ cz,
    const float* __restrict__ stageW, const float* __restrict__ stageb,
    const float* __restrict__ psW1, const float* __restrict__ psb1,
    float* __restrict__ Dps, float* __restrict__ fbps,
    const float* __restrict__ gfW, const float* __restrict__ gfb,
    const float* __restrict__ irW1, const float* __restrict__ irb1,
    float* __restrict__ Cir, float* __restrict__ fbir,
    unsigned short* __restrict__ Bhi,
    const float* __restrict__ eW1, const float* __restrict__ eW2,
    unsigned short* __restrict__ eW1T, unsigned short* __restrict__ eW2T)
{
    __shared__ float s_t[32][33];
    int bid = blockIdx.x;
    const int tid = threadIdx.x;

    if (bid < MG_PREP) {
        if (bid == 0 && tid < 32) cz[tid] = 0;
        const int t = bid * 4 + (tid >> 6);
        const int lane = tid & 63;
        const float* row = hidden + (size_t)t * DMODEL;
        float4 v0 = ((const float4*)row)[lane * 2 + 0];
        float4 v1 = ((const float4*)row)[lane * 2 + 1];
        float s = v0.x + v0.y + v0.z + v0.w + v1.x + v1.y + v1.z + v1.w;
        #pragma unroll
        for (int m = 1; m < 64; m <<= 1) s += __shfl_xor(s, m);
        const float mu = s * (1.0f / DMODEL);
        float sq = 0.f;
        { float d;
          d = v0.x - mu; sq += d * d; d = v0.y - mu; sq += d * d;
          d = v0.z - mu; sq += d * d; d = v0.w - mu; sq += d * d;
          d = v1.x - mu; sq += d * d; d = v1.y - mu; sq += d * d;
          d = v1.z - mu; sq += d * d; d = v1.w - mu; sq += d * d; }
        #pragma unroll
        for (int m = 1; m < 64; m <<= 1) sq += __shfl_xor(sq, m);
        const float rstd = rsqrtf(sq * (1.0f / DMODEL) + 1e-5f);
        float4 g0 = ((const float4*)lng)[lane * 2 + 0];
        float4 g1 = ((const float4*)lng)[lane * 2 + 1];
        float4 b0 = ((const float4*)lnb)[lane * 2 + 0];
        float4 b1 = ((const float4*)lnb)[lane * 2 + 1];
        float h[8];
        h[0] = (v0.x - mu) * rstd * g0.x + b0.x;
        h[1] = (v0.y - mu) * rstd * g0.y + b0.y;
        h[2] = (v0.z - mu) * rstd * g0.z + b0.z;
        h[3] = (v0.w - mu) * rstd * g0.w + b0.w;
        h[4] = (v1.x - mu) * rstd * g1.x + b1.x;
        h[5] = (v1.y - mu) * rstd * g1.y + b1.y;
        h[6] = (v1.z - mu) * rstd * g1.z + b1.z;
        h[7] = (v1.w - mu) * rstd * g1.w + b1.w;
        const int q8 = ((t >> 1) & 3) * 8;
        ushort4 H0, H1;
        H0.x = f2h(h[0]); H0.y = f2h(h[1]); H0.z = f2h(h[2]); H0.w = f2h(h[3]);
        H1.x = f2h(h[4]); H1.y = f2h(h[5]); H1.z = f2h(h[6]); H1.w = f2h(h[7]);
        unsigned short* pa = Ahi + (size_t)t * RIN;
        const int dst = (lane >> 2) * 32 + (((lane & 3) * 8) ^ q8);
        *(ushort4*)&pa[dst] = H0;  *(ushort4*)&pa[dst + 4] = H1;
        const float fv = feat[(size_t)t * FFEAT + lane];
        const int fd = DMODEL + (lane & 32) + ((lane & 31) ^ q8);
        pa[fd] = f2h(fv);
        return;
    }
    bid -= MG_PREP;

    if (bid < MG_FPS) {
        const int g = bid / 33;
        const int f = (bid % 33) * 2 + (tid >> 7);
        const int c = tid & 127;
        const float* Wt = psW1 + (size_t)g * RIN * DRH + (size_t)DMODEL * DRH;
        float acc = 0.f;
        if (f < 64) {
            for (int j = 0; j < DFEMB; ++j) acc = fmaf(stageW[f * DFEMB + j], Wt[(size_t)j * DRH + c], acc);
            Dps[((size_t)g * 64 + f) * DRH + c] = acc;
        } else if (f == 64) {
            for (int j = 0; j < DFEMB; ++j) acc = fmaf(stageb[j], Wt[(size_t)j * DRH + c], acc);
            fbps[g * DRH + c] = acc + psb1[g * DRH + c];
        }
        return;
    }
    bid -= MG_FPS;

    if (bid < MG_FIR) {
        const int g = bid / 5;
        const int f = (bid % 5) * 2 + (tid >> 7);
        const int c = tid & 127;
        const float* Wt = irW1 + (size_t)g * RIN * DRH + (size_t)DMODEL * DRH;
        float acc = 0.f;
        if (f < 8) {
            for (int j = 0; j < DFEMB; ++j) acc = fmaf(gfW[(size_t)(g * 8 + f) * DFEMB + j], Wt[(size_t)j * DRH + c], acc);
            Cir[((size_t)g * 8 + f) * DRH + c] = acc;
        } else if (f == 8) {
            for (int j = 0; j < DFEMB; ++j) acc = fmaf(gfb[g * DFEMB + j], Wt[(size_t)j * DRH + c], acc);
            fbir[g * DRH + c] = acc + irb1[g * DRH + c];
        }
        return;
    }
    bid -= MG_FIR;

    if (bid < MG_T2) {
        const int x = bid % 64, y = (bid / 64) % 8, z = bid / 512;
        const float* in = z ? irW1 : psW1;
        unsigned short* outHi = Bhi + (z ? (size_t)1024 * RIN : 0);
        const int tilesN = DRH >> 5;
        const int ko = (x / tilesN) << 5;
        const int no = (x % tilesN) << 5;
        const int r = tid >> 3, c0 = (tid & 7) * 4;
        {
            float4 v = *(const float4*)(in + (size_t)y * RIN * DRH + (size_t)(ko + r) * DRH + no + c0);
            s_t[r][c0] = v.x; s_t[r][c0 + 1] = v.y; s_t[r][c0 + 2] = v.z; s_t[r][c0 + 3] = v.w;
        }
        __syncthreads();
        float vv[4];
        #pragma unroll
        for (int j = 0; j < 4; ++j) vv[j] = s_t[c0 + j][r];
        const int col = no + r;
        const int q8 = ((col >> 1) & 3) * 8;
        ushort4 hi;
        hi.x = f2h(vv[0]); hi.y = f2h(vv[1]); hi.z = f2h(vv[2]); hi.w = f2h(vv[3]);
        *(ushort4*)(outHi + (size_t)y * DRH * RIN + (size_t)col * RIN + ko + (c0 ^ q8)) = hi;
        return;
    }
    bid -= MG_T2;

    {
        const int x = bid % 128, y = (bid / 128) % 16, z = bid / 2048;
        const int K = z ? DHID : DMODEL;
        const int N = z ? DMODEL : DHID;
        const float* in = z ? eW2 : eW1;
        unsigned short* outHi = z ? eW2T : eW1T;
        const long BS = (long)DMODEL * DHID;
        const int tilesN = N >> 5;
        const int ko = (x / tilesN) << 5;
        const int no = (x % tilesN) << 5;
        const int r = tid >> 3, c0 = (tid & 7) * 4;
        {
            float4 v = *(const float4*)(in + (size_t)y * BS + (size_t)(ko + r) * N + no + c0);
            s_t[r][c0] = v.x; s_t[r][c0 + 1] = v.y; s_t[r][c0 + 2] = v.z; s_t[r][c0 + 3] = v.w;
        }
        __syncthreads();
        float vv[4];
        #pragma unroll
        for (int j = 0; j < 4; ++j) vv[j] = s_t[c0 + j][r];
        const int col = no + r;
        const int q8 = ((col >> 1) & 3) * 8;
        ushort4 hi;
        hi.x = f2h(vv[0]); hi.y = f2h(vv[1]); hi.z = f2h(vv[2]); hi.w = f2h(vv[3]);
        *(ushort4*)(outHi + (size_t)y * BS + (size_t)col * K + ko + (c0 ^ q8)) = hi;
    }
}

// ---------- Mega kernel 2: fold-dependent jobs (Dps transpose + ir tail) ----------
__global__ __launch_bounds__(256) void k_mega2(
    const float* __restrict__ Dps, const float* __restrict__ Cir,
    unsigned short* __restrict__ Bhi)
{
    __shared__ float s_t[32][33];
    int bid = blockIdx.x;
    const int tid = threadIdx.x;

    if (bid < 64) {
        const int x = bid % 8, b = bid / 8;
        const int tilesN = DRH >> 5;
        const int ko = (x / tilesN) << 5;
        const int no = (x % tilesN) << 5;
        const int r = tid >> 3, c0 = (tid & 7) * 4;
        {
            float4 v = *(const float4*)(Dps + (size_t)b * 64 * DRH + (size_t)(ko + r) * DRH + no + c0);
            s_t[r][c0] = v.x; s_t[r][c0 + 1] = v.y; s_t[r][c0 + 2] = v.z; s_t[r][c0 + 3] = v.w;
        }
        __syncthreads();
        float vv[4];
        #pragma unroll
        for (int j = 0; j < 4; ++j) vv[j] = s_t[c0 + j][r];
        const int col = no + r;
        const int q8 = ((col >> 1) & 3) * 8;
        ushort4 hi;
        hi.x = f2h(vv[0]); hi.y = f2h(vv[1]); hi.z = f2h(vv[2]); hi.w = f2h(vv[3]);
        *(ushort4*)(Bhi + (size_t)b * DRH * RIN + (size_t)col * RIN + 512 + ko + (c0 ^ q8)) = hi;
        return;
    }
    bid -= 64;

    {
        const int g = bid;
        const int c = tid & 127;
        const int h = tid >> 7;
        const int col = 1024 + g * DRH + c;
        const int q8 = ((col >> 1) & 3) * 8;
        unsigned short* ph = Bhi + (size_t)col * RIN + DMODEL;
        for (int f = h * 32; f < h * 32 + 32; ++f) {
            float v = ((f >> 3) == g) ? Cir[((size_t)g * 8 + (f & 7)) * DRH + c] : 0.f;
            const int d = (f & 32) + ((f & 31) ^ q8);
            ph[d] = f2h(v);
        }
    }
}

// ---------- Kernel 2: router GEMM, N-panel-fused: one block computes PS and IR panels of group g ----------
// grid (T/128, 8). A tile staged once, two B panels (rows g*128.. and (8+g)*128..).
// LDS layout/offsets byte-identical to R13 (stride-32 rows, no new bank conflicts);
// 16 MFMA per barrier pair (2x R13), 1024 blocks (0.5x).
__global__ __launch_bounds__(512) void k_rgemm(
    const unsigned short* __restrict__ Ahi, const unsigned short* __restrict__ Bhi,
    const float* __restrict__ fbps, const float* __restrict__ psW2, const float* __restrict__ psb2,
    const float* __restrict__ fbir, const float* __restrict__ irW2, const float* __restrict__ irb2,
    float* __restrict__ glog, float* __restrict__ ilog)
{
    __shared__ unsigned short sAh[3][128 * 32];
    __shared__ unsigned short sBh[3][2][128 * 32];
    __shared__ float s_redPS[2][4][64];
    __shared__ float s_redIR[2][4][64][2];

    const int tid = threadIdx.x, lane = tid & 63, w = tid >> 6;
    const int t0 = blockIdx.x * 128, g = blockIdx.y;
    const int wm = w >> 2, wn = w & 3;
    const int arow = lane & 15, koff = (lane >> 4) * 8;
    const int q8r = ((arow >> 1) & 3) * 8;

    int aoff[4], boff[2];
    #pragma unroll
    for (int m = 0; m < 4; ++m) aoff[m] = (wm * 64 + m * 16 + arow) * 32 + (koff ^ q8r);
    #pragma unroll
    for (int n = 0; n < 2; ++n) boff[n] = (wn * 32 + n * 16 + arow) * 32 + (koff ^ q8r);

    const int srow = w * 16 + (lane >> 2);
    const int sgr = (lane & 3) * 8;
    const unsigned short* gAh = Ahi + (size_t)(t0 + srow) * RIN + sgr;
    const unsigned short* gB0 = Bhi + (size_t)(g * 128 + srow) * RIN + sgr;          // PS panel
    const unsigned short* gB1 = Bhi + (size_t)((8 + g) * 128 + srow) * RIN + sgr;    // IR panel

    f32x4 acc[2][4][2];
    #pragma unroll
    for (int p = 0; p < 2; ++p)
        #pragma unroll
        for (int m = 0; m < 4; ++m)
            #pragma unroll
            for (int n = 0; n < 2; ++n) { acc[p][m][n].x = 0.f; acc[p][m][n].y = 0.f; acc[p][m][n].z = 0.f; acc[p][m][n].w = 0.f; }

    auto STAGE = [&](int b, int kt) {
        const int kk = kt * 32;
        gl_lds16(gAh + kk, &sAh[b][w * 512]);
        gl_lds16(gB0 + kk, &sBh[b][0][w * 512]);
        gl_lds16(gB1 + kk, &sBh[b][1][w * 512]);
    };

    STAGE(0, 0);
    STAGE(1, 1);
    for (int kt = 0; kt < 18; ++kt) {
        const int slot = kt % 3;
        if (kt + 2 < 18) { STAGE((kt + 2) % 3, kt + 2); WAIT_VM(6); }
        else if (kt + 1 < 18) { WAIT_VM(3); }
        else { WAIT_VM(0); }
        __builtin_amdgcn_s_barrier();
        __builtin_amdgcn_sched_barrier(0);
        f16x8 ah[4];
        #pragma unroll
        for (int m = 0; m < 4; ++m) ah[m] = *(const f16x8*)&sAh[slot][aoff[m]];
        #pragma unroll
        for (int p = 0; p < 2; ++p)
            #pragma unroll
            for (int n = 0; n < 2; ++n) {
                f16x8 b = *(const f16x8*)&sBh[slot][p][boff[n]];
                #pragma unroll
                for (int m = 0; m < 4; ++m) acc[p][m][n] = MFMA16F(ah[m], b, acc[p][m][n]);
            }
        __builtin_amdgcn_s_barrier();
    }

    // fused second layer: PS (panel 0) and IR (panel 1) epilogues for group g
    const int q = lane >> 4;
    {
        float r0[4][4] = {};
        #pragma unroll
        for (int n = 0; n < 2; ++n) {
            const int cg = wn * 32 + n * 16 + arow;
            const float b1 = fbps[g * DRH + cg];
            const float w2 = psW2[g * DRH + cg];
            #pragma unroll
            for (int m = 0; m < 4; ++m)
                #pragma unroll
                for (int j = 0; j < 4; ++j)
                    r0[m][j] += gelu_f(acc[0][m][n][j] + b1) * w2;
        }
        #pragma unroll
        for (int mk = 1; mk < 16; mk <<= 1)
            #pragma unroll
            for (int m = 0; m < 4; ++m)
                #pragma unroll
                for (int j = 0; j < 4; ++j) r0[m][j] += __shfl_xor(r0[m][j], mk);
        if (arow == 0) {
            #pragma unroll
            for (int m = 0; m < 4; ++m)
                #pragma unroll
                for (int j = 0; j < 4; ++j)
                    s_redPS[wm][wn][m * 16 + q * 4 + j] = r0[m][j];
        }
    }
    {
        float r0[4][4] = {}, r1[4][4] = {};
        #pragma unroll
        for (int n = 0; n < 2; ++n) {
            const int cg = wn * 32 + n * 16 + arow;
            const float b1 = fbir[g * DRH + cg];
            const float w20 = irW2[(size_t)(g * DRH + cg) * NES + 0];
            const float w21 = irW2[(size_t)(g * DRH + cg) * NES + 1];
            #pragma unroll
            for (int m = 0; m < 4; ++m)
                #pragma unroll
                for (int j = 0; j < 4; ++j) {
                    const float v = gelu_f(acc[1][m][n][j] + b1);
                    r0[m][j] = fmaf(v, w20, r0[m][j]);
                    r1[m][j] = fmaf(v, w21, r1[m][j]);
                }
        }
        #pragma unroll
        for (int mk = 1; mk < 16; mk <<= 1)
            #pragma unroll
            for (int m = 0; m < 4; ++m)
                #pragma unroll
                for (int j = 0; j < 4; ++j) {
                    r0[m][j] += __shfl_xor(r0[m][j], mk);
                    r1[m][j] += __shfl_xor(r1[m][j], mk);
                }
        if (arow == 0) {
            #pragma unroll
            for (int m = 0; m < 4; ++m)
                #pragma unroll
                for (int j = 0; j < 4; ++j) {
                    s_redIR[wm][wn][m * 16 + q * 4 + j][0] = r0[m][j];
                    s_redIR[wm][wn][m * 16 + q * 4 + j][1] = r1[m][j];
                }
        }
    }
    __syncthreads();
    if (tid < 128) {
        const int row = tid;
        const int wmm = row >> 6, rl = row & 63;
        float vps = s_redPS[wmm][0][rl] + s_redPS[wmm][1][rl]
                  + s_redPS[wmm][2][rl] + s_redPS[wmm][3][rl];
        glog[(size_t)(t0 + row) * NG + g] = vps + psb2[g];
        float v0 = s_redIR[wmm][0][rl][0] + s_redIR[wmm][1][rl][0]
                 + s_redIR[wmm][2][rl][0] + s_redIR[wmm][3][rl][0];
        float v1 = s_redIR[wmm][0][rl][1] + s_redIR[wmm][1][rl][1]
                 + s_redIR[wmm][2][rl][1] + s_redIR[wmm][3][rl][1];
        const size_t bidx = ((size_t)(t0 + row) * NG + g) * NES;
        ilog[bidx + 0] = v0 + irb2[g * NES + 0];
        ilog[bidx + 1] = v1 + irb2[g * NES + 1];
    }
}

// ---------- Kernel 2b: finalize, block-aggregated atomics ----------
#define MARGIN 4e-3f
__global__ __launch_bounds__(256) void hg_finalize2(
    const float* __restrict__ glog_buf, const float* __restrict__ ilog_buf,
    int* __restrict__ counts, int* __restrict__ nfix, int* __restrict__ fix_list,
    int* __restrict__ list_tok, float* __restrict__ list_w, int* __restrict__ list_slot)
{
    __shared__ int s_cnt[NE];
    __shared__ int s_base[NE];
    __shared__ int s_fcnt, s_fbase;

    const int tid = threadIdx.x;
    const int t = blockIdx.x * 256 + tid;
    if (tid < NE) s_cnt[tid] = 0;
    if (tid == 0) s_fcnt = 0;
    __syncthreads();

    float gl[NG];
    *(float4*)&gl[0] = ((const float4*)(glog_buf + (size_t)t * NG))[0];
    *(float4*)&gl[4] = ((const float4*)(glog_buf + (size_t)t * NG))[1];
    int i1 = 0; float m1 = gl[0];
    #pragma unroll
    for (int g = 1; g < NG; ++g) if (gl[g] > m1) { m1 = gl[g]; i1 = g; }
    int i2 = -1; float m2 = -3.4e38f;
    #pragma unroll
    for (int g = 0; g < NG; ++g) if (g != i1 && gl[g] > m2) { m2 = gl[g]; i2 = g; }
    float m3 = -3.4e38f;
    #pragma unroll
    for (int g = 0; g < NG; ++g) if (g != i1 && g != i2 && gl[g] > m3) m3 = gl[g];

    const float ila0 = ilog_buf[((size_t)t * NG + i1) * NES + 0];
    const float ila1 = ilog_buf[((size_t)t * NG + i1) * NES + 1];
    const float ilb0 = ilog_buf[((size_t)t * NG + i2) * NES + 0];
    const float ilb1 = ilog_buf[((size_t)t * NG + i2) * NES + 1];

    const bool flag = ((m2 - m3) < MARGIN) || (fabsf(ila1 - ila0) < MARGIN)
                   || (fabsf(ilb1 - ilb0) < MARGIN);

    const float ex = expf(m2 - m1);
    const float inv = 1.0f / (1.0f + ex);
    const int   gsel[2] = {i1, i2};
    const float wsel[2] = {inv, ex * inv};
    const int   ksel[2] = {(ila1 > ila0) ? 1 : 0, (ilb1 > ilb0) ? 1 : 0};

    int eid[2] = {0, 0}, lo[2] = {0, 0}, fo = 0;
    if (!flag) {
        #pragma unroll
        for (int s = 0; s < 2; ++s) {
            eid[s] = gsel[s] * NES + ksel[s];
            lo[s] = atomicAdd(&s_cnt[eid[s]], 1);
        }
    } else {
        fo = atomicAdd(&s_fcnt, 1);
    }
    __syncthreads();
    if (tid < NE) s_base[tid] = atomicAdd(&counts[tid], s_cnt[tid]);
    if (tid == 16) s_fbase = atomicAdd(nfix, s_fcnt);
    __syncthreads();

    if (!flag) {
        #pragma unroll
        for (int s = 0; s < 2; ++s) {
            const int pos = s_base[eid[s]] + lo[s];
            list_tok[(size_t)eid[s] * T_TOKENS + pos] = t;
            list_w[(size_t)eid[s] * T_TOKENS + pos] = wsel[s];
            list_slot[(size_t)eid[s] * T_TOKENS + pos] = s;
        }
    } else {
        fix_list[s_fbase + fo] = t;
    }
}

// ---------- Kernel 2c: exact fp32 fixup, 4-wave parallel, unrolled ----------
__global__ __launch_bounds__(256) void hg_fixup(
    const float* __restrict__ hidden, const float* __restrict__ feat,
    const float* __restrict__ lng, const float* __restrict__ lnb,
    const float* __restrict__ stageW, const float* __restrict__ stageb,
    const float* __restrict__ gfW, const float* __restrict__ gfb,
    const float* __restrict__ psW1, const float* __restrict__ psb1,
    const float* __restrict__ psW2, const float* __restrict__ psb2,
    const float* __restrict__ irW1, const float* __restrict__ irb1,
    const float* __restrict__ irW2, const float* __restrict__ irb2,
    const int* __restrict__ nfix, const int* __restrict__ fix_list,
    int* __restrict__ counts, int* __restrict__ list_tok, float* __restrict__ list_w,
    int* __restrict__ list_slot)
{
    __shared__ float s_rin[RIN];
    __shared__ float s_tail[2][DFEMB];
    __shared__ float s_gl[NG];
    __shared__ float s_part[4][2];
    __shared__ int s_sel[2];
    __shared__ float s_wsel[2];

    const int tid = threadIdx.x, lane = tid & 63, w = tid >> 6;
    const int nf = nfix[0];
    for (int idx = blockIdx.x; idx < nf; idx += gridDim.x) {
        const int t = fix_list[idx];
        if (w == 0) {
            const float* row = hidden + (size_t)t * DMODEL;
            float4 v0 = ((const float4*)row)[lane * 2 + 0];
            float4 v1 = ((const float4*)row)[lane * 2 + 1];
            float s = v0.x + v0.y + v0.z + v0.w + v1.x + v1.y + v1.z + v1.w;
            #pragma unroll
            for (int m = 1; m < 64; m <<= 1) s += __shfl_xor(s, m);
            const float mu = s * (1.0f / DMODEL);
            float sq = 0.f;
            { float d;
              d = v0.x - mu; sq += d * d; d = v0.y - mu; sq += d * d;
              d = v0.z - mu; sq += d * d; d = v0.w - mu; sq += d * d;
              d = v1.x - mu; sq += d * d; d = v1.y - mu; sq += d * d;
              d = v1.z - mu; sq += d * d; d = v1.w - mu; sq += d * d; }
            #pragma unroll
            for (int m = 1; m < 64; m <<= 1) sq += __shfl_xor(sq, m);
            const float rstd = rsqrtf(sq * (1.0f / DMODEL) + 1e-5f);
            float4 g0 = ((const float4*)lng)[lane * 2 + 0];
            float4 g1 = ((const float4*)lng)[lane * 2 + 1];
            float4 b0 = ((const float4*)lnb)[lane * 2 + 0];
            float4 b1 = ((const float4*)lnb)[lane * 2 + 1];
            s_rin[lane * 8 + 0] = (v0.x - mu) * rstd * g0.x + b0.x;
            s_rin[lane * 8 + 1] = (v0.y - mu) * rstd * g0.y + b0.y;
            s_rin[lane * 8 + 2] = (v0.z - mu) * rstd * g0.z + b0.z;
            s_rin[lane * 8 + 3] = (v0.w - mu) * rstd * g0.w + b0.w;
            s_rin[lane * 8 + 4] = (v1.x - mu) * rstd * g1.x + b1.x;
            s_rin[lane * 8 + 5] = (v1.y - mu) * rstd * g1.y + b1.y;
            s_rin[lane * 8 + 6] = (v1.z - mu) * rstd * g1.z + b1.z;
            s_rin[lane * 8 + 7] = (v1.w - mu) * rstd * g1.w + b1.w;
        } else if (w == 1) {
            float se = stageb[lane];
            #pragma unroll 8
            for (int f = 0; f < FFEAT; ++f)
                se = fmaf(feat[(size_t)t * FFEAT + f], stageW[f * DFEMB + lane], se);
            s_rin[DMODEL + lane] = se;
        }
        __syncthreads();

        #pragma unroll
        for (int gi = 0; gi < 2; ++gi) {
            const int g = w * 2 + gi;
            float a0 = psb1[g * DRH + lane];
            float a1 = psb1[g * DRH + 64 + lane];
            const float* W = psW1 + (size_t)g * RIN * DRH;
            #pragma unroll 8
            for (int k = 0; k < RIN; ++k) {
                const float r = s_rin[k];
                a0 = fmaf(r, W[(size_t)k * DRH + lane], a0);
                a1 = fmaf(r, W[(size_t)k * DRH + 64 + lane], a1);
            }
            float p = gelu_f(a0) * psW2[g * DRH + lane] + gelu_f(a1) * psW2[g * DRH + 64 + lane];
            #pragma unroll
            for (int m = 1; m < 64; m <<= 1) p += __shfl_xor(p, m);
            if (lane == 0) s_gl[g] = p + psb2[g];
        }
        __syncthreads();

        if (tid == 0) {
            int i1 = 0; float m1 = s_gl[0];
            #pragma unroll
            for (int g = 1; g < NG; ++g) if (s_gl[g] > m1) { m1 = s_gl[g]; i1 = g; }
            int i2 = -1; float m2 = -3.4e38f;
            #pragma unroll
            for (int g = 0; g < NG; ++g) if (g != i1 && s_gl[g] > m2) { m2 = s_gl[g]; i2 = g; }
            const float ex = expf(m2 - m1);
            const float inv = 1.0f / (1.0f + ex);
            s_sel[0] = i1; s_sel[1] = i2;
            s_wsel[0] = inv; s_wsel[1] = ex * inv;
        }
        __syncthreads();

        const int pr = w >> 1;
        const int gsel = s_sel[pr];
        if ((w & 1) == 0) {
            float ge = gfb[gsel * DFEMB + lane];
            #pragma unroll
            for (int f = 0; f < 8; ++f)
                ge = fmaf(feat[(size_t)t * FFEAT + gsel * 8 + f],
                          gfW[(size_t)(gsel * 8 + f) * DFEMB + lane], ge);
            s_tail[pr][lane] = ge;
        }
        __syncthreads();

        {
            const int col = (w & 1) * 64 + lane;
            float a = irb1[gsel * DRH + col];
            const float* W = irW1 + (size_t)gsel * RIN * DRH + col;
            #pragma unroll 8
            for (int k = 0; k < DMODEL; ++k)
                a = fmaf(s_rin[k], W[(size_t)k * DRH], a);
            #pragma unroll 8
            for (int k = 0; k < DFEMB; ++k)
                a = fmaf(s_tail[pr][k], W[(size_t)(DMODEL + k) * DRH], a);
            const float v = gelu_f(a);
            float e0 = v * irW2[(size_t)(gsel * DRH + col) * NES + 0];
            float e1 = v * irW2[(size_t)(gsel * DRH + col) * NES + 1];
            #pragma unroll
            for (int m = 1; m < 64; m <<= 1) {
                e0 += __shfl_xor(e0, m);
                e1 += __shfl_xor(e1, m);
            }
            if (lane == 0) { s_part[w][0] = e0; s_part[w][1] = e1; }
        }
        __syncthreads();

        if (tid == 0) {
            #pragma unroll
            for (int p2 = 0; p2 < 2; ++p2) {
                const float e0 = s_part[p2 * 2][0] + s_part[p2 * 2 + 1][0];
                const float e1 = s_part[p2 * 2][1] + s_part[p2 * 2 + 1][1];
                const int eid = s_sel[p2] * NES + ((e1 > e0) ? 1 : 0);
                const int pos = atomicAdd(&counts[eid], 1);
                list_tok[(size_t)eid * T_TOKENS + pos] = t;
                list_w[(size_t)eid * T_TOKENS + pos] = s_wsel[p2];
                list_slot[(size_t)eid * T_TOKENS + pos] = p2;
            }
        }
        __syncthreads();
    }
}

// ---------- Kernel 3a: expert GEMM1 -> ehbuf (depth-3 pipeline) ----------
__global__ __launch_bounds__(256) void k_e1(
    const unsigned short* __restrict__ Ahi,
    const unsigned short* __restrict__ eW1T, const float* __restrict__ eb1,
    const int* __restrict__ counts, const int* __restrict__ list_tok,
    const int* __restrict__ list_slot, unsigned short* __restrict__ ehbuf)
{
    __shared__ unsigned short sA[3][64 * 32];
    __shared__ unsigned short sB[3][256 * 32];
    __shared__ int s_tok[64];
    __shared__ int s_pair[64];

    const int e = blockIdx.y;
    const int cnt = counts[e];
    const int base = blockIdx.x * 64;
    if (base >= cnt) return;
    const int nrow = min(64, cnt - base);
    const int tid = threadIdx.x, lane = tid & 63, w = tid >> 6;

    if (tid < 64) {
        const int src = base + ((tid < nrow) ? tid : (nrow - 1));
        s_tok[tid] = list_tok[(size_t)e * T_TOKENS + src];
        s_pair[tid] = s_tok[tid] * 2 + list_slot[(size_t)e * T_TOKENS + src];
    }
    __syncthreads();

    const int srow = w * 16 + (lane >> 2);
    const int stok = s_tok[srow];
    const int qcor = ((srow >> 1) & 3) ^ ((stok >> 1) & 3);
    const unsigned short* gA = Ahi + (size_t)stok * RIN + 8 * ((lane & 3) ^ qcor);
    const int sgr = (lane & 3) * 8;
    const unsigned short* gB[4];
    #pragma unroll
    for (int i = 0; i < 4; ++i)
        gB[i] = eW1T + (size_t)e * DHID * DMODEL + (size_t)(w * 64 + i * 16 + (lane >> 2)) * DMODEL + sgr;

    const int arow = lane & 15, koff = (lane >> 4) * 8;
    const int q8r = ((arow >> 1) & 3) * 8;
    int aoff[4], boff[4];
    #pragma unroll
    for (int m = 0; m < 4; ++m) aoff[m] = (m * 16 + arow) * 32 + (koff ^ q8r);
    #pragma unroll
    for (int n = 0; n < 4; ++n) boff[n] = (w * 64 + n * 16 + arow) * 32 + (koff ^ q8r);

    f32x4 acc[4][4];
    #pragma unroll
    for (int m = 0; m < 4; ++m)
        #pragma unroll
        for (int n = 0; n < 4; ++n) { acc[m][n].x = 0.f; acc[m][n].y = 0.f; acc[m][n].z = 0.f; acc[m][n].w = 0.f; }

    auto STAGE = [&](int b, int kt) {
        const int kk = kt * 32;
        gl_lds16(gA + kk, &sA[b][w * 512]);
        #pragma unroll
        for (int i = 0; i < 4; ++i) gl_lds16(gB[i] + kk, &sB[b][w * 2048 + i * 512]);
    };

    STAGE(0, 0);
    STAGE(1, 1);
    for (int kt = 0; kt < 16; ++kt) {
        const int slot = kt % 3;
        if (kt + 2 < 16) { STAGE((kt + 2) % 3, kt + 2); WAIT_VM(10); }
        else if (kt + 1 < 16) { WAIT_VM(5); }
        else { WAIT_VM(0); }
        __builtin_amdgcn_s_barrier();
        __builtin_amdgcn_sched_barrier(0);
        f16x8 a[4];
        #pragma unroll
        for (int m = 0; m < 4; ++m) a[m] = *(const f16x8*)&sA[slot][aoff[m]];
        #pragma unroll
        for (int n = 0; n < 4; ++n) {
            f16x8 b = *(const f16x8*)&sB[slot][boff[n]];
            #pragma unroll
            for (int m = 0; m < 4; ++m) acc[m][n] = MFMA16F(a[m], b, acc[m][n]);
        }
        __builtin_amdgcn_s_barrier();
    }

    const int q = lane >> 4;
    #pragma unroll
    for (int m = 0; m < 4; ++m)
        #pragma unroll
        for (int n = 0; n < 4; ++n) {
            const int col = w * 64 + n * 16 + arow;
            const float bv = eb1[e * DHID + col];
            #pragma unroll
            for (int j = 0; j < 4; ++j) {
                const int rr = m * 16 + q * 4 + j;
                if (rr < nrow) {   // padded rows alias real ehbuf rows with a different swizzle key -> must skip
                    const size_t d = (size_t)s_pair[rr] * DHID
                                   + (col & 0xE0) + ((col & 31) ^ (((rr >> 1) & 3) * 8));
                    ehbuf[d] = f2h(gelu_f(acc[m][n][j] + bv));
                }
            }
        }
}

// ---------- Kernel 3b: expert GEMM2 -> contrib (depth-3 pipeline) ----------
__global__ __launch_bounds__(256) void k_e2(
    const unsigned short* __restrict__ ehbuf,
    const unsigned short* __restrict__ eW2T, const float* __restrict__ eb2,
    const float* __restrict__ alpha_p,
    const int* __restrict__ counts, const int* __restrict__ list_tok,
    const float* __restrict__ list_w, const int* __restrict__ list_slot,
    unsigned short* __restrict__ contrib)
{
    __shared__ unsigned short sA[3][64 * 32];
    __shared__ unsigned short sB[3][256 * 32];
    __shared__ int s_pair[64];
    __shared__ float s_w[64];

    const int e = blockIdx.y;
    const int cnt = counts[e];
    const int base = blockIdx.x * 64;
    if (base >= cnt) return;
    const int ch = blockIdx.z;
    const int nrow = min(64, cnt - base);
    const int tid = threadIdx.x, lane = tid & 63, w = tid >> 6;

    if (tid < 64) {
        const int src = base + ((tid < nrow) ? tid : (nrow - 1));
        const int tok = list_tok[(size_t)e * T_TOKENS + src];
        s_pair[tid] = tok * 2 + list_slot[(size_t)e * T_TOKENS + src];
        s_w[tid] = (tid < nrow) ? list_w[(size_t)e * T_TOKENS + base + tid] : 0.f;
    }
    __syncthreads();

    const int srow = w * 16 + (lane >> 2);
    const unsigned short* gA = ehbuf + (size_t)s_pair[srow] * DHID + (lane & 3) * 8;
    const int sgr = (lane & 3) * 8;
    const unsigned short* gB[4];
    #pragma unroll
    for (int i = 0; i < 4; ++i)
        gB[i] = eW2T + (size_t)e * DMODEL * DHID
              + (size_t)(ch * 256 + w * 64 + i * 16 + (lane >> 2)) * DHID + sgr;

    const int arow = lane & 15, koff = (lane >> 4) * 8;
    const int q8r = ((arow >> 1) & 3) * 8;
    int aoff[4], boff[4];
    #pragma unroll
    for (int m = 0; m < 4; ++m) aoff[m] = (m * 16 + arow) * 32 + (koff ^ q8r);
    #pragma unroll
    for (int n = 0; n < 4; ++n) boff[n] = (w * 64 + n * 16 + arow) * 32 + (koff ^ q8r);

    f32x4 acc[4][4];
    #pragma unroll
    for (int m = 0; m < 4; ++m)
        #pragma unroll
        for (int n = 0; n < 4; ++n) { acc[m][n].x = 0.f; acc[m][n].y = 0.f; acc[m][n].z = 0.f; acc[m][n].w = 0.f; }

    auto STAGE = [&](int b, int kt) {
        const int kk = kt * 32;
        gl_lds16(gA + kk, &sA[b][w * 512]);
        #pragma unroll
        for (int i = 0; i < 4; ++i) gl_lds16(gB[i] + kk, &sB[b][w * 2048 + i * 512]);
    };

    STAGE(0, 0);
    STAGE(1, 1);
    for (int kt = 0; kt < 8; ++kt) {
        const int slot = kt % 3;
        if (kt + 2 < 8) { STAGE((kt + 2) % 3, kt + 2); WAIT_VM(10); }
        else if (kt + 1 < 8) { WAIT_VM(5); }
        else { WAIT_VM(0); }
        __builtin_amdgcn_s_barrier();
        __builtin_amdgcn_sched_barrier(0);
        f16x8 a[4];
        #pragma unroll
        for (int m = 0; m < 4; ++m) a[m] = *(const f16x8*)&sA[slot][aoff[m]];
        #pragma unroll
        for (int n = 0; n < 4; ++n) {
            f16x8 b = *(const f16x8*)&sB[slot][boff[n]];
            #pragma unroll
            for (int m = 0; m < 4; ++m) acc[m][n] = MFMA16F(a[m], b, acc[m][n]);
        }
        __builtin_amdgcn_s_barrier();
    }

    const float alpha = alpha_p[0];
    const int q = lane >> 4;
    #pragma unroll
    for (int m = 0; m < 4; ++m)
        #pragma unroll
        for (int n = 0; n < 4; ++n) {
            const int col = ch * 256 + w * 64 + n * 16 + arow;
            const float b2v = eb2[e * DMODEL + col];
            #pragma unroll
            for (int j = 0; j < 4; ++j) {
                const int r = m * 16 + q * 4 + j;
                if (r < nrow)
                    contrib[(size_t)s_pair[r] * DMODEL + col] =
                        f2h(s_w[r] * alpha * (acc[m][n][j] + b2v));
            }
        }
}

// ---------- Kernel 4: combine out = hidden + c0 + c1 ----------
__global__ __launch_bounds__(256) void k_combine(
    const float* __restrict__ hidden, const unsigned short* __restrict__ contrib,
    float* __restrict__ out)
{
    const size_t gid = (size_t)blockIdx.x * 256 + threadIdx.x;
    const int t = (int)(gid >> 6);
    const int c = (int)(gid & 63) * 8;
    const float* hp = hidden + (size_t)t * DMODEL + c;
    float4 h0 = ((const float4*)hp)[0];
    float4 h1 = ((const float4*)hp)[1];
    const unsigned short* c0p = contrib + ((size_t)t * 2 + 0) * DMODEL + c;
    const unsigned short* c1p = contrib + ((size_t)t * 2 + 1) * DMODEL + c;
    ushort4 a0 = ((const ushort4*)c0p)[0], a1 = ((const ushort4*)c0p)[1];
    ushort4 b0 = ((const ushort4*)c1p)[0], b1 = ((const ushort4*)c1p)[1];
    float4 o0, o1;
    o0.x = h0.x + h2f(a0.x) + h2f(b0.x);
    o0.y = h0.y + h2f(a0.y) + h2f(b0.y);
    o0.z = h0.z + h2f(a0.z) + h2f(b0.z);
    o0.w = h0.w + h2f(a0.w) + h2f(b0.w);
    o1.x = h1.x + h2f(a1.x) + h2f(b1.x);
    o1.y = h1.y + h2f(a1.y) + h2f(b1.y);
    o1.z = h1.z + h2f(a1.z) + h2f(b1.z);
    o1.w = h1.w + h2f(a1.w) + h2f(b1.w);
    float* op = out + (size_t)t * DMODEL + c;
    ((float4*)op)[0] = o0;
    ((float4*)op)[1] = o1;
}

// ---------- launch ----------
extern "C" void kernel_launch(void* const* d_in, const int* in_sizes, int n_in,
                              void* d_out, int out_size, void* d_ws, size_t ws_size,
                              hipStream_t stream) {
    const float* hidden = (const float*)d_in[0];
    const float* feat   = (const float*)d_in[1];
    const float* ln_g   = (const float*)d_in[2];
    const float* ln_b   = (const float*)d_in[3];
    const float* stageW = (const float*)d_in[4];
    const float* stageb = (const float*)d_in[5];
    const float* gfW    = (const float*)d_in[6];
    const float* gfb    = (const float*)d_in[7];
    const float* psW1   = (const float*)d_in[8];
    const float* psb1   = (const float*)d_in[9];
    const float* psW2   = (const float*)d_in[10];
    const float* psb2   = (const float*)d_in[11];
    const float* irW1   = (const float*)d_in[12];
    const float* irb1   = (const float*)d_in[13];
    const float* irW2   = (const float*)d_in[14];
    const float* irb2   = (const float*)d_in[15];
    const float* eW1    = (const float*)d_in[16];
    const float* eb1    = (const float*)d_in[17];
    const float* eW2    = (const float*)d_in[18];
    const float* eb2    = (const float*)d_in[19];
    const float* alpha  = (const float*)d_in[20];

    float* out = (float*)d_out;

    char* p = (char*)d_ws;
    unsigned short* Ahi = (unsigned short*)p; p += (size_t)T_TOKENS * RIN * 2;
    unsigned short* Bhi = (unsigned short*)p; p += (size_t)2048 * RIN * 2;
    unsigned short* eW1T = (unsigned short*)p; p += (size_t)NE * DHID * DMODEL * 2;
    unsigned short* eW2T = (unsigned short*)p; p += (size_t)NE * DMODEL * DHID * 2;
    unsigned short* contrib = (unsigned short*)p; p += (size_t)T_TOKENS * 2 * DMODEL * 2;
    unsigned short* ehbuf = (unsigned short*)p; p += (size_t)T_TOKENS * 2 * DHID * 2;
    float* Dps = (float*)p;   p += (size_t)NG * 64 * DRH * 4;
    float* Cir = (float*)p;   p += (size_t)NG * 8 * DRH * 4;
    float* fbps = (float*)p;  p += (size_t)NG * DRH * 4;
    float* fbir = (float*)p;  p += (size_t)NG * DRH * 4;
    float* glog_buf = (float*)p; p += (size_t)T_TOKENS * NG * 4;
    float* ilog_buf = (float*)p; p += (size_t)T_TOKENS * NG * NES * 4;
    int* counts = (int*)p;    p += 128;
    int* nfix = counts + 16;
    int* fix_list = (int*)p;  p += (size_t)T_TOKENS * 4;
    int* list_tok = (int*)p;  p += (size_t)NE * T_TOKENS * 4;
    float* list_w = (float*)p; p += (size_t)NE * T_TOKENS * 4;
    int* list_slot = (int*)p; p += (size_t)NE * T_TOKENS * 4;

    k_mega1<<<MG_TOTAL, 256, 0, stream>>>(
        hidden, feat, ln_g, ln_b, Ahi, counts,
        stageW, stageb, psW1, psb1, Dps, fbps,
        gfW, gfb, irW1, irb1, Cir, fbir,
        Bhi, eW1, eW2, eW1T, eW2T);

    k_mega2<<<72, 256, 0, stream>>>(Dps, Cir, Bhi);

    k_rgemm<<<dim3(T_TOKENS / 128, 8), 512, 0, stream>>>(
        Ahi, Bhi, fbps, psW2, psb2, fbir, irW2, irb2, glog_buf, ilog_buf);

    hg_finalize2<<<T_TOKENS / 256, 256, 0, stream>>>(
        glog_buf, ilog_buf, counts, nfix, fix_list, list_tok, list_w, list_slot);

    hg_fixup<<<1024, 256, 0, stream>>>(
        hidden, feat, ln_g, ln_b, stageW, stageb, gfW, gfb,
        psW1, psb1, psW2, psb2, irW1, irb1, irW2, irb2,
        nfix, fix_list, counts, list_tok, list_w, list_slot);

    k_e1<<<dim3(T_TOKENS / 64, NE), 256, 0, stream>>>(
        Ahi, eW1T, eb1, counts, list_tok, list_slot, ehbuf);

    k_e2<<<dim3(T_TOKENS / 64, NE, 2), 256, 0, stream>>>(
        ehbuf, eW2T, eb2, alpha, counts, list_tok, list_w, list_slot, contrib);

    k_combine<<<(T_TOKENS * DMODEL / 8) / 256, 256, 0, stream>>>(hidden, contrib, out);
}